// Round 5
// baseline (172.541 us; speedup 1.0000x reference)
//
#include <hip/hip_runtime.h>
#include <hip/hip_bf16.h>

typedef __hip_bfloat16 bf16;
typedef __attribute__((ext_vector_type(8))) short short8_t;
typedef __attribute__((ext_vector_type(4))) short short4_t;
typedef __attribute__((ext_vector_type(4))) float f32x4;

#define B_SZ   2
#define T_SEQ  2048
#define C_DIM  1024
#define NH     16
#define NKV    4
#define HD     64
#define QKVW   1536          // fused QKV row width (1024 Q | 256 K | 256 V)
#define MTOK   (B_SZ * T_SEQ)

#define LOG2_BASE_OVER_32 0.4152410118609203f
#define Q_SCALE 0.1803368801111204f   // 0.125 * log2(e)

__device__ __forceinline__ short f2bs(float f) {
    unsigned u = __float_as_uint(f);
    u += 0x7FFFu + ((u >> 16) & 1u);
    return (short)(u >> 16);
}
__device__ __forceinline__ short f2bs_trunc(float f) {
    return (short)(__float_as_uint(f) >> 16);
}
__device__ __forceinline__ float bs2f(short s) {
    unsigned u = ((unsigned)(unsigned short)s) << 16;
    return __uint_as_float(u);
}
// lane <-> lane^1 exchange, pure VALU (quad_perm [1,0,3,2])
__device__ __forceinline__ float dpp_xor1(float x) {
    return __int_as_float(
        __builtin_amdgcn_update_dpp(0, __float_as_int(x), 0xB1, 0xF, 0xF, true));
}
// bare v_exp_f32 (2^x)
__device__ __forceinline__ float fast_exp2(float x) {
    float r;
    asm("v_exp_f32 %0, %1" : "=v"(r) : "v"(x));
    return r;
}
// pack hi16(lo), hi16(hi) -> one dword (two bf16, truncating) in 1 v_perm_b32
__device__ __forceinline__ unsigned pack_bf16_trunc(float lo, float hi) {
    return __builtin_amdgcn_perm(__float_as_uint(hi), __float_as_uint(lo),
                                 0x07060302u);
}
// direct HBM -> LDS, 16B per lane. LDS dest = (wave-uniform base) + lane*16.
__device__ __forceinline__ void gload_lds16(const short* g, short* l) {
    __builtin_amdgcn_global_load_lds(
        (const __attribute__((address_space(1))) void*)g,
        (__attribute__((address_space(3))) void*)l, 16, 0, 0);
}

// ---------------------------------------------------------------------------
// Fused prep (unchanged): x->bf16, weight transposes, bias concat, RoPE table
// ---------------------------------------------------------------------------
__device__ __forceinline__ void transpose_tile(
    const float* __restrict__ W, short* __restrict__ Wt,
    int K, int N, int n0, int k0, int tid)
{
    __shared__ float tile[32][33];
    int tx = tid & 31, ty = tid >> 5;
    #pragma unroll
    for (int i = 0; i < 4; ++i)
        tile[ty + 8 * i][tx] = W[(size_t)(k0 + ty + 8 * i) * N + n0 + tx];
    __syncthreads();
    #pragma unroll
    for (int i = 0; i < 4; ++i)
        Wt[(size_t)(n0 + ty + 8 * i) * K + k0 + tx] = f2bs(tile[tx][ty + 8 * i]);
}

__global__ __launch_bounds__(256) void prep_kernel(
    const float* __restrict__ x,
    const float* __restrict__ w_q, const float* __restrict__ w_k,
    const float* __restrict__ w_v, const float* __restrict__ w_o,
    const float* __restrict__ b_q, const float* __restrict__ b_k,
    const float* __restrict__ b_v,
    short* __restrict__ Xb, short* __restrict__ Wqkv, short* __restrict__ Wto,
    float* __restrict__ Bqkv, float2* __restrict__ Tab)
{
    int blk = blockIdx.x, tid = threadIdx.x;
    if (blk < 4096) {
        int i = blk * 1024 + tid * 4;
        float4 v = *(const float4*)(x + i);
        short4_t o;
        o[0] = f2bs(v.x); o[1] = f2bs(v.y); o[2] = f2bs(v.z); o[3] = f2bs(v.w);
        *(short4_t*)(Xb + i) = o;
    } else if (blk < 5120) {
        int l = blk - 4096;
        transpose_tile(w_q, Wqkv, C_DIM, C_DIM, (l & 31) * 32, (l >> 5) * 32, tid);
    } else if (blk < 5376) {
        int l = blk - 5120;
        transpose_tile(w_k, Wqkv + (size_t)1024 * C_DIM, C_DIM, 256,
                       (l & 7) * 32, (l >> 3) * 32, tid);
    } else if (blk < 5632) {
        int l = blk - 5376;
        transpose_tile(w_v, Wqkv + (size_t)1280 * C_DIM, C_DIM, 256,
                       (l & 7) * 32, (l >> 3) * 32, tid);
    } else if (blk < 6656) {
        int l = blk - 5632;
        transpose_tile(w_o, Wto, C_DIM, C_DIM, (l & 31) * 32, (l >> 5) * 32, tid);
    } else if (blk < 6662) {
        int i = (blk - 6656) * 256 + tid;
        float v;
        if (i < 1024)      v = b_q[i];
        else if (i < 1280) v = b_k[i - 1024];
        else               v = b_v[i - 1280];
        Bqkv[i] = v;
    } else {
        int idx = (blk - 6662) * 256 + tid;
        int t = idx >> 5, i = idx & 31;
        float ang = (float)t * exp2f(-(float)i * LOG2_BASE_OVER_32);
        Tab[idx] = make_float2(cosf(ang), sinf(ang));
    }
}

// ---------------------------------------------------------------------------
// QKV GEMM (unchanged from R3): m97-pattern K-loop, BK=64, global_load_lds,
// XOR-swizzled source + swizzled ds_read.
// ---------------------------------------------------------------------------
__global__ __launch_bounds__(256) void gemm_qkv(
    const short* __restrict__ A, const short* __restrict__ Bt,
    const float* __restrict__ bias, const float2* __restrict__ Tab,
    short* __restrict__ QKVb, short* __restrict__ Vt)
{
    __shared__ __align__(16) short smem[12288];     // 24 KB: A 128x64 | B 64x64
    short* sA0 = smem;                              // 8192 shorts
    short* sB0 = smem + 8192;                       // 4096 shorts

    const int K = C_DIM;
    int m0 = blockIdx.y * 128;
    int n0 = blockIdx.x * 64;
    int tid  = threadIdx.x;
    int w    = tid >> 6, lane = tid & 63;
    int quad = lane >> 4, l16 = lane & 15;
    int wm = w & 1, wn = w >> 1;

    f32x4 acc[4][2] = {};

    for (int k0 = 0; k0 < K; k0 += 64) {
        #pragma unroll
        for (int it = 0; it < 4; ++it) {
            int i = (w * 4 + it) * 64 + lane;
            int row = i >> 3, p = i & 7;
            int gc = k0 + ((p ^ (row & 7)) << 3);
            gload_lds16(A + (size_t)(m0 + row) * K + gc, sA0 + (w * 4 + it) * 512);
        }
        #pragma unroll
        for (int it = 0; it < 2; ++it) {
            int i = (w * 2 + it) * 64 + lane;
            int row = i >> 3, p = i & 7;
            int gc = k0 + ((p ^ (row & 7)) << 3);
            gload_lds16(Bt + (size_t)(n0 + row) * K + gc, sB0 + (w * 2 + it) * 512);
        }
        __syncthreads();

        #pragma unroll
        for (int ks = 0; ks < 2; ++ks) {
            short8_t af[4], bf[2];
            #pragma unroll
            for (int mt = 0; mt < 4; ++mt) {
                int r = wm * 64 + mt * 16 + l16;
                int g = ks * 4 + quad;
                af[mt] = *(const short8_t*)&sA0[r * 64 + ((g ^ (r & 7)) << 3)];
            }
            #pragma unroll
            for (int nt = 0; nt < 2; ++nt) {
                int r = wn * 32 + nt * 16 + l16;
                int g = ks * 4 + quad;
                bf[nt] = *(const short8_t*)&sB0[r * 64 + ((g ^ (r & 7)) << 3)];
            }
            #pragma unroll
            for (int mt = 0; mt < 4; ++mt)
                #pragma unroll
                for (int nt = 0; nt < 2; ++nt)
                    acc[mt][nt] = __builtin_amdgcn_mfma_f32_16x16x32_bf16(
                        af[mt], bf[nt], acc[mt][nt], 0, 0, 0);
        }
        __syncthreads();
    }

    if (n0 < 1280) {
        float scale = (n0 < 1024) ? Q_SCALE : 1.0f;
        float sgn   = (l16 & 1) ? 1.0f : -1.0f;
        #pragma unroll
        for (int nt = 0; nt < 2; ++nt) {
            int col = n0 + wn * 32 + nt * 16 + l16;
            int ip  = (col & 63) >> 1;
            float bv = bias[col];
            #pragma unroll
            for (int mt = 0; mt < 4; ++mt) {
                #pragma unroll
                for (int r = 0; r < 4; ++r) {
                    int row = m0 + wm * 64 + mt * 16 + quad * 4 + r;
                    float v = acc[mt][nt][r] + bv;
                    float po = dpp_xor1(v);
                    float2 cs = Tab[(row & (T_SEQ - 1)) * 32 + ip];
                    float res = (v * cs.x + sgn * po * cs.y) * scale;
                    QKVb[(size_t)row * QKVW + col] = f2bs(res);
                }
            }
        }
    } else {
        short (*sT)[136] = (short(*)[136])smem;
        #pragma unroll
        for (int nt = 0; nt < 2; ++nt) {
            int col_l = wn * 32 + nt * 16 + l16;
            float bv = bias[n0 + col_l];
            #pragma unroll
            for (int mt = 0; mt < 4; ++mt)
                #pragma unroll
                for (int r = 0; r < 4; ++r)
                    sT[col_l][wm * 64 + mt * 16 + quad * 4 + r] =
                        f2bs(acc[mt][nt][r] + bv);
        }
        __syncthreads();
        int d0 = n0 - 1280;
        #pragma unroll
        for (int it = 0; it < 4; ++it) {
            int slot = tid + 256 * it;
            int dl = slot >> 4, seg = (slot & 15) * 8;
            *(short8_t*)(Vt + (size_t)(d0 + dl) * MTOK + m0 + seg) =
                *(const short8_t*)&sT[dl][seg];
        }
    }
}

// ---------------------------------------------------------------------------
// O-projection GEMM (unchanged from R3)
// ---------------------------------------------------------------------------
__global__ __launch_bounds__(256) void gemm_mfma_o(
    const short* __restrict__ A, const short* __restrict__ Bt,
    const float* __restrict__ bias, float* __restrict__ C,
    int M, int N, int K)
{
    __shared__ __align__(16) short smem[12288];
    short* sA0 = smem;
    short* sB0 = smem + 8192;

    int m0 = blockIdx.y * 128;
    int n0 = blockIdx.x * 64;
    int tid  = threadIdx.x;
    int w    = tid >> 6, lane = tid & 63;
    int quad = lane >> 4, l16 = lane & 15;
    int wm = w & 1, wn = w >> 1;

    f32x4 acc[4][2] = {};

    for (int k0 = 0; k0 < K; k0 += 64) {
        #pragma unroll
        for (int it = 0; it < 4; ++it) {
            int i = (w * 4 + it) * 64 + lane;
            int row = i >> 3, p = i & 7;
            int gc = k0 + ((p ^ (row & 7)) << 3);
            gload_lds16(A + (size_t)(m0 + row) * K + gc, sA0 + (w * 4 + it) * 512);
        }
        #pragma unroll
        for (int it = 0; it < 2; ++it) {
            int i = (w * 2 + it) * 64 + lane;
            int row = i >> 3, p = i & 7;
            int gc = k0 + ((p ^ (row & 7)) << 3);
            gload_lds16(Bt + (size_t)(n0 + row) * K + gc, sB0 + (w * 2 + it) * 512);
        }
        __syncthreads();

        #pragma unroll
        for (int ks = 0; ks < 2; ++ks) {
            short8_t af[4], bf[2];
            #pragma unroll
            for (int mt = 0; mt < 4; ++mt) {
                int r = wm * 64 + mt * 16 + l16;
                int g = ks * 4 + quad;
                af[mt] = *(const short8_t*)&sA0[r * 64 + ((g ^ (r & 7)) << 3)];
            }
            #pragma unroll
            for (int nt = 0; nt < 2; ++nt) {
                int r = wn * 32 + nt * 16 + l16;
                int g = ks * 4 + quad;
                bf[nt] = *(const short8_t*)&sB0[r * 64 + ((g ^ (r & 7)) << 3)];
            }
            #pragma unroll
            for (int mt = 0; mt < 4; ++mt)
                #pragma unroll
                for (int nt = 0; nt < 2; ++nt)
                    acc[mt][nt] = __builtin_amdgcn_mfma_f32_16x16x32_bf16(
                        af[mt], bf[nt], acc[mt][nt], 0, 0, 0);
        }
        __syncthreads();
    }

    #pragma unroll
    for (int mt = 0; mt < 4; ++mt) {
        #pragma unroll
        for (int nt = 0; nt < 2; ++nt) {
            int col = n0 + wn * 32 + nt * 16 + l16;
            float bv = bias[col];
            #pragma unroll
            for (int r = 0; r < 4; ++r) {
                int row = m0 + wm * 64 + mt * 16 + quad * 4 + r;
                C[(size_t)row * N + col] = acc[mt][nt][r] + bv;
            }
        }
    }
}

// ---------------------------------------------------------------------------
// MFMA flash attention v13: PAIRED Q-TILES (split-K reverted).
// 512 blocks, 4 waves; wave = 1 head x 2 ADJACENT q-tiles (2p, 2p+1), which
// provably share the same causal chunk count ((2p)>>2 == (2p+1)>>2).
// Mechanism (R2/R4 falsified LDS-count & tail theories -> latency-bound):
//   - each kf/vf LDS read now feeds BOTH tiles' MFMAs: LDS reads and staging
//     per unit work HALVE;
//   - two independent dependency streams per wave (QK_B overlaps softmax_A)
//     fill the stall slots that phase-locked 4-block CUs could not.
// Retains: in-register P via key-permuted V, double-buffered staging with
// one barrier/chunk, bare v_exp_f32, defer-max per tile, v_perm packs,
// s_setprio around MFMA clusters.
// ---------------------------------------------------------------------------
__global__ __launch_bounds__(256) void attn_mfma13(
    const short* __restrict__ QKV, const short* __restrict__ Vt,
    short* __restrict__ O)
{
    __shared__ __align__(16) short sK [2][64][72];
    __shared__ __align__(16) short sVt[2][64][72];

    const int tid  = threadIdx.x;
    const int w    = tid >> 6;
    const int lane = tid & 63;
    const int quad = lane >> 4;
    const int l16  = lane & 15;

    int blk = blockIdx.x;
    int grp = blk & 7;                 // (b,kvh)
    int pr  = 63 - (blk >> 3);         // pair index, long pairs first
    int kvh = grp & 3;
    int b   = grp >> 2;
    int h   = kvh * 4 + w;
    int tqA = pr * 2;
    int tqB = pr * 2 + 1;
    int ct  = tqB >> 2;                // == tqA>>2 (adjacent pairing)
    int tgA = tqA * 16 + l16;
    int tgB = tqB * 16 + l16;

    // Q frags for both tiles (already roped + scaled)
    const short* qA = QKV + ((size_t)(b * T_SEQ) + tqA * 16 + l16) * QKVW + h * HD;
    const short* qB = QKV + ((size_t)(b * T_SEQ) + tqB * 16 + l16) * QKVW + h * HD;
    short8_t qf0a = *(const short8_t*)(qA + quad * 8);
    short8_t qf1a = *(const short8_t*)(qA + quad * 8 + 32);
    short8_t qf0b = *(const short8_t*)(qB + quad * 8);
    short8_t qf1b = *(const short8_t*)(qB + quad * 8 + 32);

    const short* kbase  = QKV + (size_t)b * T_SEQ * QKVW + 1024 + kvh * HD;
    const short* vtbase = Vt + (size_t)(kvh * HD) * MTOK + b * T_SEQ;

    float m_a = -INFINITY, l_a = 0.f;   // quad-partial row sums
    float m_b = -INFINITY, l_b = 0.f;
    f32x4 oaccA[4], oaccB[4];
    #pragma unroll
    for (int dt = 0; dt < 4; ++dt) {
        oaccA[dt] = (f32x4){0.f, 0.f, 0.f, 0.f};
        oaccB[dt] = (f32x4){0.f, 0.f, 0.f, 0.f};
    }

    const int kkey = tid >> 3, kd = (tid & 7) * 8;
    const int vdim = tid >> 3;
    const int s8   = tid & 7;
    const int vseg = s8 * 8;
    // permuted base position for V staging (key-perm matching in-register P)
    const int P0 = ((s8 & 4) << 3) | ((s8 & 1) << 4) | ((s8 & 2) << 1);

    short8_t kr[2], vr[2];
    #pragma unroll
    for (int it = 0; it < 2; ++it) {
        kr[it] = *(const short8_t*)(kbase + (size_t)(kkey + 32 * it) * QKVW + kd);
        vr[it] = *(const short8_t*)(vtbase + (size_t)(vdim + 32 * it) * MTOK + vseg);
    }
    #pragma unroll
    for (int it = 0; it < 2; ++it) {
        *(short8_t*)&sK[0][kkey + 32 * it][kd] = kr[it];
        union { short8_t v; short4_t hh[2]; } u; u.v = vr[it];
        *(short4_t*)&sVt[0][vdim + 32 * it][P0]     = u.hh[0];
        *(short4_t*)&sVt[0][vdim + 32 * it][P0 + 8] = u.hh[1];
    }
    __syncthreads();

    for (int c = 0; c <= ct; ++c) {
        const int buf = c & 1;

        if (c < ct) {
            int jn = (c + 1) * 64;
            #pragma unroll
            for (int it = 0; it < 2; ++it) {
                kr[it] = *(const short8_t*)(kbase + (size_t)(jn + kkey + 32 * it) * QKVW + kd);
                vr[it] = *(const short8_t*)(vtbase + (size_t)(vdim + 32 * it) * MTOK + jn + vseg);
            }
        }

        // S^T = K Q^T for BOTH tiles; each kf read feeds 2 MFMAs
        f32x4 saccA[4], saccB[4];
        __builtin_amdgcn_s_setprio(1);
        #pragma unroll
        for (int kt = 0; kt < 4; ++kt) {
            short8_t kf0 = *(const short8_t*)&sK[buf][l16 + 16 * kt][quad * 8];
            short8_t kf1 = *(const short8_t*)&sK[buf][l16 + 16 * kt][quad * 8 + 32];
            f32x4 za = {0.f, 0.f, 0.f, 0.f};
            f32x4 zb = {0.f, 0.f, 0.f, 0.f};
            za = __builtin_amdgcn_mfma_f32_16x16x32_bf16(kf0, qf0a, za, 0, 0, 0);
            zb = __builtin_amdgcn_mfma_f32_16x16x32_bf16(kf0, qf0b, zb, 0, 0, 0);
            za = __builtin_amdgcn_mfma_f32_16x16x32_bf16(kf1, qf1a, za, 0, 0, 0);
            zb = __builtin_amdgcn_mfma_f32_16x16x32_bf16(kf1, qf1b, zb, 0, 0, 0);
            saccA[kt] = za;
            saccB[kt] = zb;
        }
        __builtin_amdgcn_s_setprio(0);

        // hoist first-half V fragments; LDS latency overlaps softmax VALU
        short8_t vf0[4];
        #pragma unroll
        for (int dt = 0; dt < 4; ++dt)
            vf0[dt] = *(const short8_t*)&sVt[buf][16 * dt + l16][quad * 8];

        if (c == ct) {
            int j0 = c * 64;
            #pragma unroll
            for (int kt = 0; kt < 4; ++kt)
                #pragma unroll
                for (int r = 0; r < 4; ++r) {
                    int key = j0 + 16 * kt + quad * 4 + r;
                    if (key > tgA) saccA[kt][r] = -INFINITY;
                    if (key > tgB) saccB[kt][r] = -INFINITY;
                }
        }

        // ---- tile A softmax ----
        {
            float v0 = fmaxf(fmaxf(saccA[0][0], saccA[0][1]), fmaxf(saccA[0][2], saccA[0][3]));
            float v1 = fmaxf(fmaxf(saccA[1][0], saccA[1][1]), fmaxf(saccA[1][2], saccA[1][3]));
            float v2 = fmaxf(fmaxf(saccA[2][0], saccA[2][1]), fmaxf(saccA[2][2], saccA[2][3]));
            float v3 = fmaxf(fmaxf(saccA[3][0], saccA[3][1]), fmaxf(saccA[3][2], saccA[3][3]));
            float vloc = fmaxf(fmaxf(v0, v1), fmaxf(v2, v3));
            if (!__all(vloc <= m_a + 8.0f)) {
                float vmax = fmaxf(vloc, __shfl_xor(vloc, 16));
                vmax = fmaxf(vmax, __shfl_xor(vmax, 32));
                float mnew = fmaxf(m_a, vmax);
                float al = fast_exp2(m_a - mnew);
                m_a = mnew;
                l_a *= al;
                #pragma unroll
                for (int r = 0; r < 4; ++r) {
                    float alr = __shfl(al, quad * 4 + r);
                    #pragma unroll
                    for (int dt = 0; dt < 4; ++dt) oaccA[dt][r] *= alr;
                }
            }
        }
        // ---- tile B softmax ----
        {
            float v0 = fmaxf(fmaxf(saccB[0][0], saccB[0][1]), fmaxf(saccB[0][2], saccB[0][3]));
            float v1 = fmaxf(fmaxf(saccB[1][0], saccB[1][1]), fmaxf(saccB[1][2], saccB[1][3]));
            float v2 = fmaxf(fmaxf(saccB[2][0], saccB[2][1]), fmaxf(saccB[2][2], saccB[2][3]));
            float v3 = fmaxf(fmaxf(saccB[3][0], saccB[3][1]), fmaxf(saccB[3][2], saccB[3][3]));
            float vloc = fmaxf(fmaxf(v0, v1), fmaxf(v2, v3));
            if (!__all(vloc <= m_b + 8.0f)) {
                float vmax = fmaxf(vloc, __shfl_xor(vloc, 16));
                vmax = fmaxf(vmax, __shfl_xor(vmax, 32));
                float mnew = fmaxf(m_b, vmax);
                float al = fast_exp2(m_b - mnew);
                m_b = mnew;
                l_b *= al;
                #pragma unroll
                for (int r = 0; r < 4; ++r) {
                    float alr = __shfl(al, quad * 4 + r);
                    #pragma unroll
                    for (int dt = 0; dt < 4; ++dt) oaccB[dt][r] *= alr;
                }
            }
        }

        // exp + pack P fragments IN REGISTER for both tiles
        short8_t pf0a, pf1a, pf0b, pf1b;
        {
            union { unsigned u[4]; short8_t v; } fa, fb;
            float psum = 0.f;
            #pragma unroll
            for (int kt = 0; kt < 4; ++kt) {
                float p0 = fast_exp2(saccA[kt][0] - m_a), p1 = fast_exp2(saccA[kt][1] - m_a);
                float p2 = fast_exp2(saccA[kt][2] - m_a), p3 = fast_exp2(saccA[kt][3] - m_a);
                psum += (p0 + p1) + (p2 + p3);
                unsigned d0 = pack_bf16_trunc(p0, p1);
                unsigned d1 = pack_bf16_trunc(p2, p3);
                if (kt < 2) { fa.u[kt * 2] = d0; fa.u[kt * 2 + 1] = d1; }
                else        { fb.u[(kt - 2) * 2] = d0; fb.u[(kt - 2) * 2 + 1] = d1; }
            }
            l_a += psum;
            pf0a = fa.v; pf1a = fb.v;
        }
        {
            union { unsigned u[4]; short8_t v; } fa, fb;
            float psum = 0.f;
            #pragma unroll
            for (int kt = 0; kt < 4; ++kt) {
                float p0 = fast_exp2(saccB[kt][0] - m_b), p1 = fast_exp2(saccB[kt][1] - m_b);
                float p2 = fast_exp2(saccB[kt][2] - m_b), p3 = fast_exp2(saccB[kt][3] - m_b);
                psum += (p0 + p1) + (p2 + p3);
                unsigned d0 = pack_bf16_trunc(p0, p1);
                unsigned d1 = pack_bf16_trunc(p2, p3);
                if (kt < 2) { fa.u[kt * 2] = d0; fa.u[kt * 2 + 1] = d1; }
                else        { fb.u[(kt - 2) * 2] = d0; fb.u[(kt - 2) * 2 + 1] = d1; }
            }
            l_b += psum;
            pf0b = fa.v; pf1b = fb.v;
        }

        // PV for both tiles; each vf read feeds 2 MFMAs
        __builtin_amdgcn_s_setprio(1);
        #pragma unroll
        for (int dt = 0; dt < 4; ++dt) {
            short8_t vf1 = *(const short8_t*)&sVt[buf][16 * dt + l16][quad * 8 + 32];
            oaccA[dt] = __builtin_amdgcn_mfma_f32_16x16x32_bf16(pf0a, vf0[dt], oaccA[dt], 0, 0, 0);
            oaccB[dt] = __builtin_amdgcn_mfma_f32_16x16x32_bf16(pf0b, vf0[dt], oaccB[dt], 0, 0, 0);
            oaccA[dt] = __builtin_amdgcn_mfma_f32_16x16x32_bf16(pf1a, vf1, oaccA[dt], 0, 0, 0);
            oaccB[dt] = __builtin_amdgcn_mfma_f32_16x16x32_bf16(pf1b, vf1, oaccB[dt], 0, 0, 0);
        }
        __builtin_amdgcn_s_setprio(0);

        // stage next chunk into the other buffer
        if (c < ct) {
            #pragma unroll
            for (int it = 0; it < 2; ++it) {
                *(short8_t*)&sK[buf ^ 1][kkey + 32 * it][kd] = kr[it];
                union { short8_t v; short4_t hh[2]; } u; u.v = vr[it];
                *(short4_t*)&sVt[buf ^ 1][vdim + 32 * it][P0]     = u.hh[0];
                *(short4_t*)&sVt[buf ^ 1][vdim + 32 * it][P0 + 8] = u.hh[1];
            }
        }
        __syncthreads();
    }

    // reduce quad-partial l across quads, write both tiles
    l_a += __shfl_xor(l_a, 16);
    l_a += __shfl_xor(l_a, 32);
    l_b += __shfl_xor(l_b, 16);
    l_b += __shfl_xor(l_b, 32);

    #pragma unroll
    for (int r = 0; r < 4; ++r) {
        int m = quad * 4 + r;
        float lra = __shfl(l_a, quad * 4 + r);
        float lrb = __shfl(l_b, quad * 4 + r);
        float inva = __builtin_amdgcn_rcpf(lra);
        float invb = __builtin_amdgcn_rcpf(lrb);
        #pragma unroll
        for (int dt = 0; dt < 4; ++dt) {
            O[((size_t)b * T_SEQ + tqA * 16 + m) * C_DIM + h * HD + 16 * dt + l16] =
                f2bs(oaccA[dt][r] * inva);
            O[((size_t)b * T_SEQ + tqB * 16 + m) * C_DIM + h * HD + 16 * dt + l16] =
                f2bs(oaccB[dt][r] * invb);
        }
    }
}

// ---------------------------------------------------------------------------
extern "C" void kernel_launch(void* const* d_in, const int* in_sizes, int n_in,
                              void* d_out, int out_size, void* d_ws, size_t ws_size,
                              hipStream_t stream)
{
    const float* x   = (const float*)d_in[0];
    const float* w_q = (const float*)d_in[1];
    const float* b_q = (const float*)d_in[2];
    const float* w_k = (const float*)d_in[3];
    const float* b_k = (const float*)d_in[4];
    const float* w_v = (const float*)d_in[5];
    const float* b_v = (const float*)d_in[6];
    const float* w_o = (const float*)d_in[7];
    const float* b_o = (const float*)d_in[8];
    float* out = (float*)d_out;

    char* ws = (char*)d_ws;
    short*  Xb   = (short*) (ws);                              // 8 MB
    short*  Ab   = (short*) (ws + ((size_t)8  << 20));         // 8 MB
    short*  QKVb = (short*) (ws + ((size_t)16 << 20));         // 12 MB
    short*  Wqkv = (short*) (ws + ((size_t)28 << 20));         // 3 MB
    short*  Wto  = (short*) (ws + ((size_t)31 << 20));         // 2 MB
    float*  Bqkv = (float*) (ws + ((size_t)33 << 20));         // 6 KB
    float2* Tab  = (float2*)(ws + ((size_t)33 << 20) + 8192);  // 512 KB
    short*  Vt   = (short*) (ws + ((size_t)34 << 20));         // 2 MB

    const int M = MTOK;   // 4096

    prep_kernel<<<6918, 256, 0, stream>>>(
        x, w_q, w_k, w_v, w_o, b_q, b_k, b_v, Xb, Wqkv, Wto, Bqkv, Tab);

    gemm_qkv<<<dim3(QKVW / 64, M / 128), 256, 0, stream>>>(
        Xb, Wqkv, Bqkv, Tab, QKVb, Vt);

    attn_mfma13<<<B_SZ * NKV * 64, 256, 0, stream>>>(QKVb, Vt, Ab);

    gemm_mfma_o<<<dim3(C_DIM / 64, M / 128), 256, 0, stream>>>(
        Ab, Wto, b_o, out, M, C_DIM, C_DIM);
}

// Round 6
// 164.628 us; speedup vs baseline: 1.0481x; 1.0481x over previous
//
#include <hip/hip_runtime.h>
#include <hip/hip_bf16.h>

typedef __hip_bfloat16 bf16;
typedef __attribute__((ext_vector_type(8))) short short8_t;
typedef __attribute__((ext_vector_type(4))) short short4_t;
typedef __attribute__((ext_vector_type(4))) float f32x4;

#define B_SZ   2
#define T_SEQ  2048
#define C_DIM  1024
#define NH     16
#define NKV    4
#define HD     64
#define QKVW   1536          // fused QKV row width (1024 Q | 256 K | 256 V)
#define MTOK   (B_SZ * T_SEQ)

#define LOG2_BASE_OVER_32 0.4152410118609203f
#define Q_SCALE 0.1803368801111204f   // 0.125 * log2(e)

__device__ __forceinline__ short f2bs(float f) {
    unsigned u = __float_as_uint(f);
    u += 0x7FFFu + ((u >> 16) & 1u);
    return (short)(u >> 16);
}
__device__ __forceinline__ short f2bs_trunc(float f) {
    return (short)(__float_as_uint(f) >> 16);
}
__device__ __forceinline__ float bs2f(short s) {
    unsigned u = ((unsigned)(unsigned short)s) << 16;
    return __uint_as_float(u);
}
// lane <-> lane^1 exchange, pure VALU (quad_perm [1,0,3,2])
__device__ __forceinline__ float dpp_xor1(float x) {
    return __int_as_float(
        __builtin_amdgcn_update_dpp(0, __float_as_int(x), 0xB1, 0xF, 0xF, true));
}
// bare v_exp_f32 (2^x)
__device__ __forceinline__ float fast_exp2(float x) {
    float r;
    asm("v_exp_f32 %0, %1" : "=v"(r) : "v"(x));
    return r;
}
// pack hi16(lo), hi16(hi) -> one dword (two bf16, truncating) in 1 v_perm_b32
__device__ __forceinline__ unsigned pack_bf16_trunc(float lo, float hi) {
    return __builtin_amdgcn_perm(__float_as_uint(hi), __float_as_uint(lo),
                                 0x07060302u);
}
// direct HBM -> LDS, 16B per lane. LDS dest = (wave-uniform base) + lane*16.
__device__ __forceinline__ void gload_lds16(const short* g, short* l) {
    __builtin_amdgcn_global_load_lds(
        (const __attribute__((address_space(1))) void*)g,
        (__attribute__((address_space(3))) void*)l, 16, 0, 0);
}

// ---------------------------------------------------------------------------
// Fused prep (unchanged): x->bf16, weight transposes, bias concat, RoPE table
// ---------------------------------------------------------------------------
__device__ __forceinline__ void transpose_tile(
    const float* __restrict__ W, short* __restrict__ Wt,
    int K, int N, int n0, int k0, int tid)
{
    __shared__ float tile[32][33];
    int tx = tid & 31, ty = tid >> 5;
    #pragma unroll
    for (int i = 0; i < 4; ++i)
        tile[ty + 8 * i][tx] = W[(size_t)(k0 + ty + 8 * i) * N + n0 + tx];
    __syncthreads();
    #pragma unroll
    for (int i = 0; i < 4; ++i)
        Wt[(size_t)(n0 + ty + 8 * i) * K + k0 + tx] = f2bs(tile[tx][ty + 8 * i]);
}

__global__ __launch_bounds__(256) void prep_kernel(
    const float* __restrict__ x,
    const float* __restrict__ w_q, const float* __restrict__ w_k,
    const float* __restrict__ w_v, const float* __restrict__ w_o,
    const float* __restrict__ b_q, const float* __restrict__ b_k,
    const float* __restrict__ b_v,
    short* __restrict__ Xb, short* __restrict__ Wqkv, short* __restrict__ Wto,
    float* __restrict__ Bqkv, float2* __restrict__ Tab)
{
    int blk = blockIdx.x, tid = threadIdx.x;
    if (blk < 4096) {
        int i = blk * 1024 + tid * 4;
        float4 v = *(const float4*)(x + i);
        short4_t o;
        o[0] = f2bs(v.x); o[1] = f2bs(v.y); o[2] = f2bs(v.z); o[3] = f2bs(v.w);
        *(short4_t*)(Xb + i) = o;
    } else if (blk < 5120) {
        int l = blk - 4096;
        transpose_tile(w_q, Wqkv, C_DIM, C_DIM, (l & 31) * 32, (l >> 5) * 32, tid);
    } else if (blk < 5376) {
        int l = blk - 5120;
        transpose_tile(w_k, Wqkv + (size_t)1024 * C_DIM, C_DIM, 256,
                       (l & 7) * 32, (l >> 3) * 32, tid);
    } else if (blk < 5632) {
        int l = blk - 5376;
        transpose_tile(w_v, Wqkv + (size_t)1280 * C_DIM, C_DIM, 256,
                       (l & 7) * 32, (l >> 3) * 32, tid);
    } else if (blk < 6656) {
        int l = blk - 5632;
        transpose_tile(w_o, Wto, C_DIM, C_DIM, (l & 31) * 32, (l >> 5) * 32, tid);
    } else if (blk < 6662) {
        int i = (blk - 6656) * 256 + tid;
        float v;
        if (i < 1024)      v = b_q[i];
        else if (i < 1280) v = b_k[i - 1024];
        else               v = b_v[i - 1280];
        Bqkv[i] = v;
    } else {
        int idx = (blk - 6662) * 256 + tid;
        int t = idx >> 5, i = idx & 31;
        float ang = (float)t * exp2f(-(float)i * LOG2_BASE_OVER_32);
        Tab[idx] = make_float2(cosf(ang), sinf(ang));
    }
}

// ---------------------------------------------------------------------------
// 128x128 GEMM K-loop building blocks: BK=64, global_load_lds staging with
// XOR-swizzled source + swizzled ds_read; 2-phase double-buffer with COUNTED
// vmcnt(8) (T4) so the next tile's 8 loads stay in flight across barriers.
// 4 waves, each owns a 64x64 output quadrant (16 MFMA per wave per ks).
// ---------------------------------------------------------------------------
#define GEMM_STAGE(dstA, dstB, Aptr, Bptr, k0)                                  \
    {                                                                           \
        _Pragma("unroll")                                                       \
        for (int it = 0; it < 4; ++it) {                                        \
            int i = (w * 4 + it) * 64 + lane;                                   \
            int row = i >> 3, p = i & 7;                                        \
            int gc = (k0) + ((p ^ (row & 7)) << 3);                             \
            gload_lds16((Aptr) + (size_t)(m0 + row) * K + gc,                   \
                        (dstA) + (w * 4 + it) * 512);                           \
        }                                                                       \
        _Pragma("unroll")                                                       \
        for (int it = 0; it < 4; ++it) {                                        \
            int i = (w * 4 + it) * 64 + lane;                                   \
            int row = i >> 3, p = i & 7;                                        \
            int gc = (k0) + ((p ^ (row & 7)) << 3);                             \
            gload_lds16((Bptr) + (size_t)(n0 + row) * K + gc,                   \
                        (dstB) + (w * 4 + it) * 512);                           \
        }                                                                       \
    }

#define GEMM_COMPUTE(srcA, srcB)                                                \
    {                                                                           \
        _Pragma("unroll")                                                       \
        for (int ks = 0; ks < 2; ++ks) {                                        \
            short8_t af[4], bf[4];                                              \
            _Pragma("unroll")                                                   \
            for (int mt = 0; mt < 4; ++mt) {                                    \
                int r = wm * 64 + mt * 16 + l16;                                \
                int g = ks * 4 + quad;                                          \
                af[mt] = *(const short8_t*)&(srcA)[r * 64 + ((g ^ (r & 7)) << 3)]; \
            }                                                                   \
            _Pragma("unroll")                                                   \
            for (int nt = 0; nt < 4; ++nt) {                                    \
                int r = wn * 64 + nt * 16 + l16;                                \
                int g = ks * 4 + quad;                                          \
                bf[nt] = *(const short8_t*)&(srcB)[r * 64 + ((g ^ (r & 7)) << 3)]; \
            }                                                                   \
            _Pragma("unroll")                                                   \
            for (int mt = 0; mt < 4; ++mt)                                      \
                _Pragma("unroll")                                               \
                for (int nt = 0; nt < 4; ++nt)                                  \
                    acc[mt][nt] = __builtin_amdgcn_mfma_f32_16x16x32_bf16(      \
                        af[mt], bf[nt], acc[mt][nt], 0, 0, 0);                  \
        }                                                                       \
    }

#define GEMM_KLOOP(Aptr, Bptr)                                                  \
    GEMM_STAGE(sA(0), sB(0), Aptr, Bptr, 0);                                    \
    for (int t = 0; t < NT; ++t) {                                              \
        int cur = t & 1;                                                        \
        if (t + 1 < NT) {                                                       \
            GEMM_STAGE(sA(cur ^ 1), sB(cur ^ 1), Aptr, Bptr, (t + 1) * 64);     \
            asm volatile("s_waitcnt vmcnt(8)" ::: "memory");                    \
        } else {                                                                \
            asm volatile("s_waitcnt vmcnt(0)" ::: "memory");                    \
        }                                                                       \
        __builtin_amdgcn_s_barrier();                                           \
        __builtin_amdgcn_sched_barrier(0);                                      \
        GEMM_COMPUTE(sA(cur), sB(cur));                                         \
        __builtin_amdgcn_sched_barrier(0);                                      \
        __builtin_amdgcn_s_barrier();                                           \
    }

// ---------------------------------------------------------------------------
// QKV GEMM v3: 128x128 tile, counted-vmcnt 2-phase. Grid (12, 32) = 384
// blocks. Epilogues: Q/K bias+RoPE(+Q_SCALE); V bias + two-pass 64-dim
// transpose via LDS -> Vt[d][token].
// ---------------------------------------------------------------------------
__global__ __launch_bounds__(256) void gemm_qkv(
    const short* __restrict__ A, const short* __restrict__ Bt,
    const float* __restrict__ bias, const float2* __restrict__ Tab,
    short* __restrict__ QKVb, short* __restrict__ Vt)
{
    __shared__ __align__(16) short smem[32768];     // 64 KB: 2 x (A 8K | B 8K)
    #define sA(b) (smem + (b) * 16384)
    #define sB(b) (smem + (b) * 16384 + 8192)

    const int K = C_DIM, NT = C_DIM / 64;
    int m0 = blockIdx.y * 128;
    int n0 = blockIdx.x * 128;
    int tid  = threadIdx.x;
    int w    = tid >> 6, lane = tid & 63;
    int quad = lane >> 4, l16 = lane & 15;
    int wm = w & 1, wn = w >> 1;

    f32x4 acc[4][4] = {};

    GEMM_KLOOP(A, Bt);

    if (n0 < 1280) {
        // Q or K: bias + RoPE (+ Q_SCALE for Q)
        float scale = (n0 < 1024) ? Q_SCALE : 1.0f;
        float sgn   = (l16 & 1) ? 1.0f : -1.0f;
        #pragma unroll
        for (int nt = 0; nt < 4; ++nt) {
            int col = n0 + wn * 64 + nt * 16 + l16;
            int ip  = (col & 63) >> 1;
            float bv = bias[col];
            #pragma unroll
            for (int mt = 0; mt < 4; ++mt) {
                #pragma unroll
                for (int r = 0; r < 4; ++r) {
                    int row = m0 + wm * 64 + mt * 16 + quad * 4 + r;
                    float v = acc[mt][nt][r] + bv;
                    float po = dpp_xor1(v);
                    float2 cs = Tab[(row & (T_SEQ - 1)) * 32 + ip];
                    float res = (v * cs.x + sgn * po * cs.y) * scale;
                    QKVb[(size_t)row * QKVW + col] = f2bs(res);
                }
            }
        }
    } else {
        // V: bias + transpose -> Vt[d][token], two 64-dim passes through LDS
        short (*sT)[136] = (short(*)[136])smem;    // 64 x 136 shorts = 17.4 KB
        #pragma unroll
        for (int h2 = 0; h2 < 2; ++h2) {
            if (wn == h2) {
                #pragma unroll
                for (int nt = 0; nt < 4; ++nt) {
                    int col_l = nt * 16 + l16;             // 0..63
                    float bv = bias[n0 + h2 * 64 + col_l];
                    #pragma unroll
                    for (int mt = 0; mt < 4; ++mt)
                        #pragma unroll
                        for (int r = 0; r < 4; ++r)
                            sT[col_l][wm * 64 + mt * 16 + quad * 4 + r] =
                                f2bs(acc[mt][nt][r] + bv);
                }
            }
            __syncthreads();
            int d0 = n0 - 1280 + h2 * 64;
            #pragma unroll
            for (int it = 0; it < 4; ++it) {
                int slot = tid + 256 * it;                 // 64 dims x 16 segs
                int dl = slot >> 4, seg = (slot & 15) * 8;
                *(short8_t*)(Vt + (size_t)(d0 + dl) * MTOK + m0 + seg) =
                    *(const short8_t*)&sT[dl][seg];
            }
            __syncthreads();
        }
    }
    #undef sA
    #undef sB
}

// ---------------------------------------------------------------------------
// O-projection GEMM v3: 128x128 tile, counted-vmcnt 2-phase, fp32 out.
// Grid (8, 32) = 256 blocks.
// ---------------------------------------------------------------------------
__global__ __launch_bounds__(256) void gemm_mfma_o(
    const short* __restrict__ A, const short* __restrict__ Bt,
    const float* __restrict__ bias, float* __restrict__ C,
    int M, int N, int K_, int unused)
{
    __shared__ __align__(16) short smem[32768];
    #define sA(b) (smem + (b) * 16384)
    #define sB(b) (smem + (b) * 16384 + 8192)

    const int K = C_DIM, NT = C_DIM / 64;
    int m0 = blockIdx.y * 128;
    int n0 = blockIdx.x * 128;
    int tid  = threadIdx.x;
    int w    = tid >> 6, lane = tid & 63;
    int quad = lane >> 4, l16 = lane & 15;
    int wm = w & 1, wn = w >> 1;

    f32x4 acc[4][4] = {};

    GEMM_KLOOP(A, Bt);

    #pragma unroll
    for (int mt = 0; mt < 4; ++mt) {
        #pragma unroll
        for (int nt = 0; nt < 4; ++nt) {
            int col = n0 + wn * 64 + nt * 16 + l16;
            float bv = bias[col];
            #pragma unroll
            for (int r = 0; r < 4; ++r) {
                int row = m0 + wm * 64 + mt * 16 + quad * 4 + r;
                C[(size_t)row * N + col] = acc[mt][nt][r] + bv;
            }
        }
    }
    #undef sA
    #undef sB
}

// ---------------------------------------------------------------------------
// MFMA flash attention v11 (reverted to the measured-best R2 form, 46.8 us):
// 1024 blocks, in-register P via key-permuted V, double-buffered staging,
// one barrier per chunk, bare v_exp_f32, defer-max, quad-partial l.
// ---------------------------------------------------------------------------
__global__ __launch_bounds__(256) void attn_mfma11(
    const short* __restrict__ QKV, const short* __restrict__ Vt,
    short* __restrict__ O)
{
    __shared__ __align__(16) short sK [2][64][72];
    __shared__ __align__(16) short sVt[2][64][72];

    const int tid  = threadIdx.x;
    const int w    = tid >> 6;
    const int lane = tid & 63;
    const int quad = lane >> 4;
    const int l16  = lane & 15;

    int blk = blockIdx.x;
    int grp = blk & 7;                 // (b,kvh)
    int tq  = 127 - (blk >> 3);        // long tiles first
    int kvh = grp & 3;
    int b   = grp >> 2;
    int h   = kvh * 4 + w;
    int ct  = tq >> 2;
    int tg  = tq * 16 + l16;

    const short* qptr = QKV + ((size_t)(b * T_SEQ) + tq * 16 + l16) * QKVW + h * HD;
    short8_t qf0 = *(const short8_t*)(qptr + quad * 8);
    short8_t qf1 = *(const short8_t*)(qptr + quad * 8 + 32);

    const short* kbase  = QKV + (size_t)b * T_SEQ * QKVW + 1024 + kvh * HD;
    const short* vtbase = Vt + (size_t)(kvh * HD) * MTOK + b * T_SEQ;

    float m_l = -INFINITY, l_l = 0.f;   // quad-partial row sum
    f32x4 oacc[4];
    #pragma unroll
    for (int dt = 0; dt < 4; ++dt) oacc[dt] = (f32x4){0.f, 0.f, 0.f, 0.f};

    const int kkey = tid >> 3, kd = (tid & 7) * 8;
    const int vdim = tid >> 3;
    const int s8   = tid & 7;
    const int vseg = s8 * 8;
    const int P0 = ((s8 & 4) << 3) | ((s8 & 1) << 4) | ((s8 & 2) << 1);

    short8_t kr[2], vr[2];
    #pragma unroll
    for (int it = 0; it < 2; ++it) {
        kr[it] = *(const short8_t*)(kbase + (size_t)(kkey + 32 * it) * QKVW + kd);
        vr[it] = *(const short8_t*)(vtbase + (size_t)(vdim + 32 * it) * MTOK + vseg);
    }

    #pragma unroll
    for (int it = 0; it < 2; ++it) {
        *(short8_t*)&sK[0][kkey + 32 * it][kd] = kr[it];
        union { short8_t v; short4_t h[2]; } u; u.v = vr[it];
        *(short4_t*)&sVt[0][vdim + 32 * it][P0]     = u.h[0];
        *(short4_t*)&sVt[0][vdim + 32 * it][P0 + 8] = u.h[1];
    }
    __syncthreads();

    for (int c = 0; c <= ct; ++c) {
        const int buf = c & 1;

        if (c < ct) {
            int jn = (c + 1) * 64;
            #pragma unroll
            for (int it = 0; it < 2; ++it) {
                kr[it] = *(const short8_t*)(kbase + (size_t)(jn + kkey + 32 * it) * QKVW + kd);
                vr[it] = *(const short8_t*)(vtbase + (size_t)(vdim + 32 * it) * MTOK + jn + vseg);
            }
        }

        f32x4 sacc[4];
        __builtin_amdgcn_s_setprio(1);
        #pragma unroll
        for (int kt = 0; kt < 4; ++kt) {
            f32x4 z = {0.f, 0.f, 0.f, 0.f};
            short8_t kf0 = *(const short8_t*)&sK[buf][l16 + 16 * kt][quad * 8];
            short8_t kf1 = *(const short8_t*)&sK[buf][l16 + 16 * kt][quad * 8 + 32];
            z = __builtin_amdgcn_mfma_f32_16x16x32_bf16(kf0, qf0, z, 0, 0, 0);
            z = __builtin_amdgcn_mfma_f32_16x16x32_bf16(kf1, qf1, z, 0, 0, 0);
            sacc[kt] = z;
        }
        __builtin_amdgcn_s_setprio(0);

        short8_t vf0[4];
        #pragma unroll
        for (int dt = 0; dt < 4; ++dt)
            vf0[dt] = *(const short8_t*)&sVt[buf][16 * dt + l16][quad * 8];

        if (c == ct) {
            int j0 = c * 64;
            #pragma unroll
            for (int kt = 0; kt < 4; ++kt)
                #pragma unroll
                for (int r = 0; r < 4; ++r)
                    if (j0 + 16 * kt + quad * 4 + r > tg) sacc[kt][r] = -INFINITY;
        }

        float v0 = fmaxf(fmaxf(sacc[0][0], sacc[0][1]), fmaxf(sacc[0][2], sacc[0][3]));
        float v1 = fmaxf(fmaxf(sacc[1][0], sacc[1][1]), fmaxf(sacc[1][2], sacc[1][3]));
        float v2 = fmaxf(fmaxf(sacc[2][0], sacc[2][1]), fmaxf(sacc[2][2], sacc[2][3]));
        float v3 = fmaxf(fmaxf(sacc[3][0], sacc[3][1]), fmaxf(sacc[3][2], sacc[3][3]));
        float vloc = fmaxf(fmaxf(v0, v1), fmaxf(v2, v3));

        if (!__all(vloc <= m_l + 8.0f)) {
            float vmax = fmaxf(vloc, __shfl_xor(vloc, 16));
            vmax = fmaxf(vmax, __shfl_xor(vmax, 32));
            float mnew = fmaxf(m_l, vmax);
            float al = fast_exp2(m_l - mnew);
            m_l = mnew;
            l_l *= al;
            #pragma unroll
            for (int r = 0; r < 4; ++r) {
                float alr = __shfl(al, quad * 4 + r);
                #pragma unroll
                for (int dt = 0; dt < 4; ++dt) oacc[dt][r] *= alr;
            }
        }

        float psum = 0.f;
        unsigned pk0, pk1, pk2, pk3, pk4, pk5, pk6, pk7;
        {
            float p0 = fast_exp2(sacc[0][0] - m_l), p1 = fast_exp2(sacc[0][1] - m_l);
            float p2 = fast_exp2(sacc[0][2] - m_l), p3 = fast_exp2(sacc[0][3] - m_l);
            psum += (p0 + p1) + (p2 + p3);
            pk0 = pack_bf16_trunc(p0, p1); pk1 = pack_bf16_trunc(p2, p3);
        }
        {
            float p0 = fast_exp2(sacc[1][0] - m_l), p1 = fast_exp2(sacc[1][1] - m_l);
            float p2 = fast_exp2(sacc[1][2] - m_l), p3 = fast_exp2(sacc[1][3] - m_l);
            psum += (p0 + p1) + (p2 + p3);
            pk2 = pack_bf16_trunc(p0, p1); pk3 = pack_bf16_trunc(p2, p3);
        }
        {
            float p0 = fast_exp2(sacc[2][0] - m_l), p1 = fast_exp2(sacc[2][1] - m_l);
            float p2 = fast_exp2(sacc[2][2] - m_l), p3 = fast_exp2(sacc[2][3] - m_l);
            psum += (p0 + p1) + (p2 + p3);
            pk4 = pack_bf16_trunc(p0, p1); pk5 = pack_bf16_trunc(p2, p3);
        }
        {
            float p0 = fast_exp2(sacc[3][0] - m_l), p1 = fast_exp2(sacc[3][1] - m_l);
            float p2 = fast_exp2(sacc[3][2] - m_l), p3 = fast_exp2(sacc[3][3] - m_l);
            psum += (p0 + p1) + (p2 + p3);
            pk6 = pack_bf16_trunc(p0, p1); pk7 = pack_bf16_trunc(p2, p3);
        }
        l_l += psum;

        short8_t pf0, pf1;
        {
            union { unsigned u[4]; short8_t v; } fa, fb;
            fa.u[0] = pk0; fa.u[1] = pk1; fa.u[2] = pk2; fa.u[3] = pk3;
            fb.u[0] = pk4; fb.u[1] = pk5; fb.u[2] = pk6; fb.u[3] = pk7;
            pf0 = fa.v; pf1 = fb.v;
        }

        __builtin_amdgcn_s_setprio(1);
        #pragma unroll
        for (int dt = 0; dt < 4; ++dt) {
            short8_t vf1 = *(const short8_t*)&sVt[buf][16 * dt + l16][quad * 8 + 32];
            oacc[dt] = __builtin_amdgcn_mfma_f32_16x16x32_bf16(pf0, vf0[dt], oacc[dt], 0, 0, 0);
            oacc[dt] = __builtin_amdgcn_mfma_f32_16x16x32_bf16(pf1, vf1, oacc[dt], 0, 0, 0);
        }
        __builtin_amdgcn_s_setprio(0);

        if (c < ct) {
            #pragma unroll
            for (int it = 0; it < 2; ++it) {
                *(short8_t*)&sK[buf ^ 1][kkey + 32 * it][kd] = kr[it];
                union { short8_t v; short4_t h[2]; } u; u.v = vr[it];
                *(short4_t*)&sVt[buf ^ 1][vdim + 32 * it][P0]     = u.h[0];
                *(short4_t*)&sVt[buf ^ 1][vdim + 32 * it][P0 + 8] = u.h[1];
            }
        }
        __syncthreads();
    }

    l_l += __shfl_xor(l_l, 16);
    l_l += __shfl_xor(l_l, 32);

    #pragma unroll
    for (int r = 0; r < 4; ++r) {
        int m = quad * 4 + r;
        float lr = __shfl(l_l, quad * 4 + r);
        float inv = __builtin_amdgcn_rcpf(lr);
        #pragma unroll
        for (int dt = 0; dt < 4; ++dt)
            O[((size_t)b * T_SEQ + tq * 16 + m) * C_DIM + h * HD + 16 * dt + l16] =
                f2bs(oacc[dt][r] * inv);
    }
}

// ---------------------------------------------------------------------------
extern "C" void kernel_launch(void* const* d_in, const int* in_sizes, int n_in,
                              void* d_out, int out_size, void* d_ws, size_t ws_size,
                              hipStream_t stream)
{
    const float* x   = (const float*)d_in[0];
    const float* w_q = (const float*)d_in[1];
    const float* b_q = (const float*)d_in[2];
    const float* w_k = (const float*)d_in[3];
    const float* b_k = (const float*)d_in[4];
    const float* w_v = (const float*)d_in[5];
    const float* b_v = (const float*)d_in[6];
    const float* w_o = (const float*)d_in[7];
    const float* b_o = (const float*)d_in[8];
    float* out = (float*)d_out;

    char* ws = (char*)d_ws;
    short*  Xb   = (short*) (ws);                              // 8 MB
    short*  Ab   = (short*) (ws + ((size_t)8  << 20));         // 8 MB
    short*  QKVb = (short*) (ws + ((size_t)16 << 20));         // 12 MB
    short*  Wqkv = (short*) (ws + ((size_t)28 << 20));         // 3 MB
    short*  Wto  = (short*) (ws + ((size_t)31 << 20));         // 2 MB
    float*  Bqkv = (float*) (ws + ((size_t)33 << 20));         // 6 KB
    float2* Tab  = (float2*)(ws + ((size_t)33 << 20) + 8192);  // 512 KB
    short*  Vt   = (short*) (ws + ((size_t)34 << 20));         // 2 MB

    const int M = MTOK;   // 4096

    prep_kernel<<<6918, 256, 0, stream>>>(
        x, w_q, w_k, w_v, w_o, b_q, b_k, b_v, Xb, Wqkv, Wto, Bqkv, Tab);

    gemm_qkv<<<dim3(QKVW / 128, M / 128), 256, 0, stream>>>(
        Xb, Wqkv, Bqkv, Tab, QKVb, Vt);

    attn_mfma11<<<B_SZ * NKV * 128, 256, 0, stream>>>(QKVb, Vt, Ab);

    gemm_mfma_o<<<dim3(C_DIM / 128, M / 128), 256, 0, stream>>>(
        Ab, Wto, b_o, out, M, C_DIM, C_DIM, 0);
}

// Round 7
// 162.672 us; speedup vs baseline: 1.0607x; 1.0120x over previous
//
#include <hip/hip_runtime.h>
#include <hip/hip_bf16.h>

typedef __hip_bfloat16 bf16;
typedef __attribute__((ext_vector_type(8))) short short8_t;
typedef __attribute__((ext_vector_type(4))) short short4_t;
typedef __attribute__((ext_vector_type(4))) float f32x4;

#define B_SZ   2
#define T_SEQ  2048
#define C_DIM  1024
#define NH     16
#define NKV    4
#define HD     64
#define QKVW   1536          // fused QKV row width (1024 Q | 256 K | 256 V)
#define MTOK   (B_SZ * T_SEQ)

#define LOG2_BASE_OVER_32 0.4152410118609203f
#define Q_SCALE 0.1803368801111204f   // 0.125 * log2(e)

__device__ __forceinline__ short f2bs(float f) {
    unsigned u = __float_as_uint(f);
    u += 0x7FFFu + ((u >> 16) & 1u);
    return (short)(u >> 16);
}
__device__ __forceinline__ short f2bs_trunc(float f) {
    return (short)(__float_as_uint(f) >> 16);
}
__device__ __forceinline__ float bs2f(short s) {
    unsigned u = ((unsigned)(unsigned short)s) << 16;
    return __uint_as_float(u);
}
// lane <-> lane^1 exchange, pure VALU (quad_perm [1,0,3,2])
__device__ __forceinline__ float dpp_xor1(float x) {
    return __int_as_float(
        __builtin_amdgcn_update_dpp(0, __float_as_int(x), 0xB1, 0xF, 0xF, true));
}
// bare v_exp_f32 (2^x)
__device__ __forceinline__ float fast_exp2(float x) {
    float r;
    asm("v_exp_f32 %0, %1" : "=v"(r) : "v"(x));
    return r;
}
// pack hi16(lo), hi16(hi) -> one dword (two bf16, truncating) in 1 v_perm_b32
__device__ __forceinline__ unsigned pack_bf16_trunc(float lo, float hi) {
    return __builtin_amdgcn_perm(__float_as_uint(hi), __float_as_uint(lo),
                                 0x07060302u);
}
// direct HBM -> LDS, 16B per lane. LDS dest = (wave-uniform base) + lane*16.
__device__ __forceinline__ void gload_lds16(const short* g, short* l) {
    __builtin_amdgcn_global_load_lds(
        (const __attribute__((address_space(1))) void*)g,
        (__attribute__((address_space(3))) void*)l, 16, 0, 0);
}

// ---------------------------------------------------------------------------
// Fused prep (unchanged): x->bf16, weight transposes, bias concat, RoPE table
// ---------------------------------------------------------------------------
__device__ __forceinline__ void transpose_tile(
    const float* __restrict__ W, short* __restrict__ Wt,
    int K, int N, int n0, int k0, int tid)
{
    __shared__ float tile[32][33];
    int tx = tid & 31, ty = tid >> 5;
    #pragma unroll
    for (int i = 0; i < 4; ++i)
        tile[ty + 8 * i][tx] = W[(size_t)(k0 + ty + 8 * i) * N + n0 + tx];
    __syncthreads();
    #pragma unroll
    for (int i = 0; i < 4; ++i)
        Wt[(size_t)(n0 + ty + 8 * i) * K + k0 + tx] = f2bs(tile[tx][ty + 8 * i]);
}

__global__ __launch_bounds__(256) void prep_kernel(
    const float* __restrict__ x,
    const float* __restrict__ w_q, const float* __restrict__ w_k,
    const float* __restrict__ w_v, const float* __restrict__ w_o,
    const float* __restrict__ b_q, const float* __restrict__ b_k,
    const float* __restrict__ b_v,
    short* __restrict__ Xb, short* __restrict__ Wqkv, short* __restrict__ Wto,
    float* __restrict__ Bqkv, float2* __restrict__ Tab)
{
    int blk = blockIdx.x, tid = threadIdx.x;
    if (blk < 4096) {
        int i = blk * 1024 + tid * 4;
        float4 v = *(const float4*)(x + i);
        short4_t o;
        o[0] = f2bs(v.x); o[1] = f2bs(v.y); o[2] = f2bs(v.z); o[3] = f2bs(v.w);
        *(short4_t*)(Xb + i) = o;
    } else if (blk < 5120) {
        int l = blk - 4096;
        transpose_tile(w_q, Wqkv, C_DIM, C_DIM, (l & 31) * 32, (l >> 5) * 32, tid);
    } else if (blk < 5376) {
        int l = blk - 5120;
        transpose_tile(w_k, Wqkv + (size_t)1024 * C_DIM, C_DIM, 256,
                       (l & 7) * 32, (l >> 3) * 32, tid);
    } else if (blk < 5632) {
        int l = blk - 5376;
        transpose_tile(w_v, Wqkv + (size_t)1280 * C_DIM, C_DIM, 256,
                       (l & 7) * 32, (l >> 3) * 32, tid);
    } else if (blk < 6656) {
        int l = blk - 5632;
        transpose_tile(w_o, Wto, C_DIM, C_DIM, (l & 31) * 32, (l >> 5) * 32, tid);
    } else if (blk < 6662) {
        int i = (blk - 6656) * 256 + tid;
        float v;
        if (i < 1024)      v = b_q[i];
        else if (i < 1280) v = b_k[i - 1024];
        else               v = b_v[i - 1280];
        Bqkv[i] = v;
    } else {
        int idx = (blk - 6662) * 256 + tid;
        int t = idx >> 5, i = idx & 31;
        float ang = (float)t * exp2f(-(float)i * LOG2_BASE_OVER_32);
        Tab[idx] = make_float2(cosf(ang), sinf(ang));
    }
}

// ---------------------------------------------------------------------------
// 128x128 GEMM K-loop building blocks (unchanged from R6): BK=64,
// global_load_lds staging, XOR-swizzled source + swizzled ds_read, 2-phase
// double-buffer with counted vmcnt(8).
// ---------------------------------------------------------------------------
#define GEMM_STAGE(dstA, dstB, Aptr, Bptr, k0)                                  \
    {                                                                           \
        _Pragma("unroll")                                                       \
        for (int it = 0; it < 4; ++it) {                                        \
            int i = (w * 4 + it) * 64 + lane;                                   \
            int row = i >> 3, p = i & 7;                                        \
            int gc = (k0) + ((p ^ (row & 7)) << 3);                             \
            gload_lds16((Aptr) + (size_t)(m0 + row) * K + gc,                   \
                        (dstA) + (w * 4 + it) * 512);                           \
        }                                                                       \
        _Pragma("unroll")                                                       \
        for (int it = 0; it < 4; ++it) {                                        \
            int i = (w * 4 + it) * 64 + lane;                                   \
            int row = i >> 3, p = i & 7;                                        \
            int gc = (k0) + ((p ^ (row & 7)) << 3);                             \
            gload_lds16((Bptr) + (size_t)(n0 + row) * K + gc,                   \
                        (dstB) + (w * 4 + it) * 512);                           \
        }                                                                       \
    }

#define GEMM_COMPUTE(srcA, srcB)                                                \
    {                                                                           \
        _Pragma("unroll")                                                       \
        for (int ks = 0; ks < 2; ++ks) {                                        \
            short8_t af[4], bf[4];                                              \
            _Pragma("unroll")                                                   \
            for (int mt = 0; mt < 4; ++mt) {                                    \
                int r = wm * 64 + mt * 16 + l16;                                \
                int g = ks * 4 + quad;                                          \
                af[mt] = *(const short8_t*)&(srcA)[r * 64 + ((g ^ (r & 7)) << 3)]; \
            }                                                                   \
            _Pragma("unroll")                                                   \
            for (int nt = 0; nt < 4; ++nt) {                                    \
                int r = wn * 64 + nt * 16 + l16;                                \
                int g = ks * 4 + quad;                                          \
                bf[nt] = *(const short8_t*)&(srcB)[r * 64 + ((g ^ (r & 7)) << 3)]; \
            }                                                                   \
            _Pragma("unroll")                                                   \
            for (int mt = 0; mt < 4; ++mt)                                      \
                _Pragma("unroll")                                               \
                for (int nt = 0; nt < 4; ++nt)                                  \
                    acc[mt][nt] = __builtin_amdgcn_mfma_f32_16x16x32_bf16(      \
                        af[mt], bf[nt], acc[mt][nt], 0, 0, 0);                  \
        }                                                                       \
    }

#define GEMM_KLOOP(Aptr, Bptr)                                                  \
    GEMM_STAGE(sA(0), sB(0), Aptr, Bptr, 0);                                    \
    for (int t = 0; t < NT; ++t) {                                              \
        int cur = t & 1;                                                        \
        if (t + 1 < NT) {                                                       \
            GEMM_STAGE(sA(cur ^ 1), sB(cur ^ 1), Aptr, Bptr, (t + 1) * 64);     \
            asm volatile("s_waitcnt vmcnt(8)" ::: "memory");                    \
        } else {                                                                \
            asm volatile("s_waitcnt vmcnt(0)" ::: "memory");                    \
        }                                                                       \
        __builtin_amdgcn_s_barrier();                                           \
        __builtin_amdgcn_sched_barrier(0);                                      \
        GEMM_COMPUTE(sA(cur), sB(cur));                                         \
        __builtin_amdgcn_sched_barrier(0);                                      \
        __builtin_amdgcn_s_barrier();                                           \
    }

// ---------------------------------------------------------------------------
// QKV GEMM (unchanged from R6): 128x128 tile, counted-vmcnt 2-phase.
// ---------------------------------------------------------------------------
__global__ __launch_bounds__(256) void gemm_qkv(
    const short* __restrict__ A, const short* __restrict__ Bt,
    const float* __restrict__ bias, const float2* __restrict__ Tab,
    short* __restrict__ QKVb, short* __restrict__ Vt)
{
    __shared__ __align__(16) short smem[32768];     // 64 KB: 2 x (A 8K | B 8K)
    #define sA(b) (smem + (b) * 16384)
    #define sB(b) (smem + (b) * 16384 + 8192)

    const int K = C_DIM, NT = C_DIM / 64;
    int m0 = blockIdx.y * 128;
    int n0 = blockIdx.x * 128;
    int tid  = threadIdx.x;
    int w    = tid >> 6, lane = tid & 63;
    int quad = lane >> 4, l16 = lane & 15;
    int wm = w & 1, wn = w >> 1;

    f32x4 acc[4][4] = {};

    GEMM_KLOOP(A, Bt);

    if (n0 < 1280) {
        // Q or K: bias + RoPE (+ Q_SCALE for Q)
        float scale = (n0 < 1024) ? Q_SCALE : 1.0f;
        float sgn   = (l16 & 1) ? 1.0f : -1.0f;
        #pragma unroll
        for (int nt = 0; nt < 4; ++nt) {
            int col = n0 + wn * 64 + nt * 16 + l16;
            int ip  = (col & 63) >> 1;
            float bv = bias[col];
            #pragma unroll
            for (int mt = 0; mt < 4; ++mt) {
                #pragma unroll
                for (int r = 0; r < 4; ++r) {
                    int row = m0 + wm * 64 + mt * 16 + quad * 4 + r;
                    float v = acc[mt][nt][r] + bv;
                    float po = dpp_xor1(v);
                    float2 cs = Tab[(row & (T_SEQ - 1)) * 32 + ip];
                    float res = (v * cs.x + sgn * po * cs.y) * scale;
                    QKVb[(size_t)row * QKVW + col] = f2bs(res);
                }
            }
        }
    } else {
        // V: bias + transpose -> Vt[d][token], two 64-dim passes through LDS
        short (*sT)[136] = (short(*)[136])smem;    // 64 x 136 shorts
        #pragma unroll
        for (int h2 = 0; h2 < 2; ++h2) {
            if (wn == h2) {
                #pragma unroll
                for (int nt = 0; nt < 4; ++nt) {
                    int col_l = nt * 16 + l16;             // 0..63
                    float bv = bias[n0 + h2 * 64 + col_l];
                    #pragma unroll
                    for (int mt = 0; mt < 4; ++mt)
                        #pragma unroll
                        for (int r = 0; r < 4; ++r)
                            sT[col_l][wm * 64 + mt * 16 + quad * 4 + r] =
                                f2bs(acc[mt][nt][r] + bv);
                }
            }
            __syncthreads();
            int d0 = n0 - 1280 + h2 * 64;
            #pragma unroll
            for (int it = 0; it < 4; ++it) {
                int slot = tid + 256 * it;                 // 64 dims x 16 segs
                int dl = slot >> 4, seg = (slot & 15) * 8;
                *(short8_t*)(Vt + (size_t)(d0 + dl) * MTOK + m0 + seg) =
                    *(const short8_t*)&sT[dl][seg];
            }
            __syncthreads();
        }
    }
    #undef sA
    #undef sB
}

// ---------------------------------------------------------------------------
// O-projection GEMM (unchanged from R6): 128x128 tile, counted-vmcnt 2-phase
// ---------------------------------------------------------------------------
__global__ __launch_bounds__(256) void gemm_mfma_o(
    const short* __restrict__ A, const short* __restrict__ Bt,
    const float* __restrict__ bias, float* __restrict__ C,
    int M, int N, int K_, int unused)
{
    __shared__ __align__(16) short smem[32768];
    #define sA(b) (smem + (b) * 16384)
    #define sB(b) (smem + (b) * 16384 + 8192)

    const int K = C_DIM, NT = C_DIM / 64;
    int m0 = blockIdx.y * 128;
    int n0 = blockIdx.x * 128;
    int tid  = threadIdx.x;
    int w    = tid >> 6, lane = tid & 63;
    int quad = lane >> 4, l16 = lane & 15;
    int wm = w & 1, wn = w >> 1;

    f32x4 acc[4][4] = {};

    GEMM_KLOOP(A, Bt);

    #pragma unroll
    for (int mt = 0; mt < 4; ++mt) {
        #pragma unroll
        for (int nt = 0; nt < 4; ++nt) {
            int col = n0 + wn * 64 + nt * 16 + l16;
            float bv = bias[col];
            #pragma unroll
            for (int r = 0; r < 4; ++r) {
                int row = m0 + wm * 64 + mt * 16 + quad * 4 + r;
                C[(size_t)row * N + col] = acc[mt][nt][r] + bv;
            }
        }
    }
    #undef sA
    #undef sB
}

// ---------------------------------------------------------------------------
// MFMA flash attention v14: 8-WAVE PAIRED BLOCKS + K-DMA staging.
// 512 blocks x 512 threads; 8 waves = 4 heads x 2 adjacent q-tiles (2p,2p+1 —
// same causal chunk count), each wave owns ONE tile (full TLP; unlike R5).
// Per CU: 2 blocks x 8 waves = 16 waves = 4/SIMD — occupancy identical to
// v11, but staging is amortized over 8 waves (global loads and LDS writes
// per unit work halve).
// K staged via global_load_lds (DMA, off the wave-issue path): pre-swizzled
// global source (granule g ^ (row&7)), linear LDS dest [64][64], swizzled
// ds_read -> conflict-uniform fragment reads without padding (rule 21).
// V stays reg-staged (its key-perm is 8B-granular, below DMA granularity).
// Retains: in-register P via key-permuted V, one barrier per chunk, bare
// v_exp_f32, defer-max, quad-partial l, v_perm packs, setprio on MFMA.
// ---------------------------------------------------------------------------
__global__ __launch_bounds__(512) void attn_mfma14(
    const short* __restrict__ QKV, const short* __restrict__ Vt,
    short* __restrict__ O)
{
    __shared__ __align__(16) short sK [2][64][64];   // swizzled granules, no pad
    __shared__ __align__(16) short sVt[2][64][72];   // padded, perm'd tokens

    const int tid  = threadIdx.x;          // 0..511
    const int w    = tid >> 6;             // 0..7
    const int lane = tid & 63;
    const int quad = lane >> 4;
    const int l16  = lane & 15;

    int blk = blockIdx.x;
    int grp = blk & 7;                     // (b,kvh): same-K/V blocks 8 apart
    int pr  = 63 - (blk >> 3);             // pair index, long pairs first
    int kvh = grp & 3;
    int b   = grp >> 2;
    int h   = kvh * 4 + (w & 3);
    int tq  = pr * 2 + (w >> 2);           // waves 0-3: tile A, 4-7: tile B
    int ct  = pr >> 1;                     // == tq>>2 for both tiles
    int tg  = tq * 16 + l16;

    // Q frags (already roped + scaled)
    const short* qptr = QKV + ((size_t)(b * T_SEQ) + tq * 16 + l16) * QKVW + h * HD;
    short8_t qf0 = *(const short8_t*)(qptr + quad * 8);
    short8_t qf1 = *(const short8_t*)(qptr + quad * 8 + 32);

    const short* kbase  = QKV + (size_t)b * T_SEQ * QKVW + 1024 + kvh * HD;
    const short* vtbase = Vt + (size_t)(kvh * HD) * MTOK + b * T_SEQ;

    float m_l = -INFINITY, l_l = 0.f;      // quad-partial row sum
    f32x4 oacc[4];
    #pragma unroll
    for (int dt = 0; dt < 4; ++dt) oacc[dt] = (f32x4){0.f, 0.f, 0.f, 0.f};

    // K DMA staging indices (512 threads cover the 64x64 tile, 16B each)
    const int kr_  = tid >> 3;             // row 0..63
    const int kg   = tid & 7;              // dest granule
    const int ksrc = (kg ^ (kr_ & 7)) << 3; // pre-swizzled source col

    // V reg staging indices (512 threads cover the 64x64 tile)
    const int vdim = tid >> 3;             // 0..63
    const int s8   = tid & 7;
    const int vseg = s8 * 8;
    const int P0   = ((s8 & 4) << 3) | ((s8 & 1) << 4) | ((s8 & 2) << 1);

    // swizzled K read granule (row&7 == l16&7 since rows are l16+16kt)
    const int c0g = quad ^ (l16 & 7);

    // prologue: stage chunk 0 into buffer 0
    gload_lds16(kbase + (size_t)kr_ * QKVW + ksrc, (short*)sK[0] + (w << 9));
    {
        short8_t v0 = *(const short8_t*)(vtbase + (size_t)vdim * MTOK + vseg);
        union { short8_t v; short4_t h[2]; } u; u.v = v0;
        *(short4_t*)&sVt[0][vdim][P0]     = u.h[0];
        *(short4_t*)&sVt[0][vdim][P0 + 8] = u.h[1];
    }
    __syncthreads();

    short8_t vr;
    for (int c = 0; c <= ct; ++c) {
        const int buf = c & 1;

        // issue next-chunk staging early: K by DMA, V to registers
        if (c < ct) {
            int jn = (c + 1) * 64;
            gload_lds16(kbase + (size_t)(jn + kr_) * QKVW + ksrc,
                        (short*)sK[buf ^ 1] + (w << 9));
            vr = *(const short8_t*)(vtbase + (size_t)vdim * MTOK + jn + vseg);
        }

        // S^T = K Q^T : rows = keys 16kt+quad*4+r, col = q = l16
        f32x4 sacc[4];
        __builtin_amdgcn_s_setprio(1);
        #pragma unroll
        for (int kt = 0; kt < 4; ++kt) {
            f32x4 z = {0.f, 0.f, 0.f, 0.f};
            const short* krow = &sK[buf][l16 + 16 * kt][0];
            short8_t kf0 = *(const short8_t*)(krow + (c0g << 3));
            short8_t kf1 = *(const short8_t*)(krow + ((c0g ^ 4) << 3));
            z = __builtin_amdgcn_mfma_f32_16x16x32_bf16(kf0, qf0, z, 0, 0, 0);
            z = __builtin_amdgcn_mfma_f32_16x16x32_bf16(kf1, qf1, z, 0, 0, 0);
            sacc[kt] = z;
        }
        __builtin_amdgcn_s_setprio(0);

        // hoist first-half V fragments; LDS latency overlaps softmax VALU
        short8_t vf0[4];
        #pragma unroll
        for (int dt = 0; dt < 4; ++dt)
            vf0[dt] = *(const short8_t*)&sVt[buf][16 * dt + l16][quad * 8];

        if (c == ct) {
            int j0 = c * 64;
            #pragma unroll
            for (int kt = 0; kt < 4; ++kt)
                #pragma unroll
                for (int r = 0; r < 4; ++r)
                    if (j0 + 16 * kt + quad * 4 + r > tg) sacc[kt][r] = -INFINITY;
        }

        float v0 = fmaxf(fmaxf(sacc[0][0], sacc[0][1]), fmaxf(sacc[0][2], sacc[0][3]));
        float v1 = fmaxf(fmaxf(sacc[1][0], sacc[1][1]), fmaxf(sacc[1][2], sacc[1][3]));
        float v2 = fmaxf(fmaxf(sacc[2][0], sacc[2][1]), fmaxf(sacc[2][2], sacc[2][3]));
        float v3 = fmaxf(fmaxf(sacc[3][0], sacc[3][1]), fmaxf(sacc[3][2], sacc[3][3]));
        float vloc = fmaxf(fmaxf(v0, v1), fmaxf(v2, v3));

        // defer-max: full (shuffle + rescale) update only when needed
        if (!__all(vloc <= m_l + 8.0f)) {
            float vmax = fmaxf(vloc, __shfl_xor(vloc, 16));
            vmax = fmaxf(vmax, __shfl_xor(vmax, 32));
            float mnew = fmaxf(m_l, vmax);
            float al = fast_exp2(m_l - mnew);
            m_l = mnew;
            l_l *= al;
            #pragma unroll
            for (int r = 0; r < 4; ++r) {
                float alr = __shfl(al, quad * 4 + r);
                #pragma unroll
                for (int dt = 0; dt < 4; ++dt) oacc[dt][r] *= alr;
            }
        }

        float psum = 0.f;
        unsigned pk0, pk1, pk2, pk3, pk4, pk5, pk6, pk7;
        {
            float p0 = fast_exp2(sacc[0][0] - m_l), p1 = fast_exp2(sacc[0][1] - m_l);
            float p2 = fast_exp2(sacc[0][2] - m_l), p3 = fast_exp2(sacc[0][3] - m_l);
            psum += (p0 + p1) + (p2 + p3);
            pk0 = pack_bf16_trunc(p0, p1); pk1 = pack_bf16_trunc(p2, p3);
        }
        {
            float p0 = fast_exp2(sacc[1][0] - m_l), p1 = fast_exp2(sacc[1][1] - m_l);
            float p2 = fast_exp2(sacc[1][2] - m_l), p3 = fast_exp2(sacc[1][3] - m_l);
            psum += (p0 + p1) + (p2 + p3);
            pk2 = pack_bf16_trunc(p0, p1); pk3 = pack_bf16_trunc(p2, p3);
        }
        {
            float p0 = fast_exp2(sacc[2][0] - m_l), p1 = fast_exp2(sacc[2][1] - m_l);
            float p2 = fast_exp2(sacc[2][2] - m_l), p3 = fast_exp2(sacc[2][3] - m_l);
            psum += (p0 + p1) + (p2 + p3);
            pk4 = pack_bf16_trunc(p0, p1); pk5 = pack_bf16_trunc(p2, p3);
        }
        {
            float p0 = fast_exp2(sacc[3][0] - m_l), p1 = fast_exp2(sacc[3][1] - m_l);
            float p2 = fast_exp2(sacc[3][2] - m_l), p3 = fast_exp2(sacc[3][3] - m_l);
            psum += (p0 + p1) + (p2 + p3);
            pk6 = pack_bf16_trunc(p0, p1); pk7 = pack_bf16_trunc(p2, p3);
        }
        l_l += psum;

        short8_t pf0, pf1;
        {
            union { unsigned u[4]; short8_t v; } fa, fb;
            fa.u[0] = pk0; fa.u[1] = pk1; fa.u[2] = pk2; fa.u[3] = pk3;
            fb.u[0] = pk4; fb.u[1] = pk5; fb.u[2] = pk6; fb.u[3] = pk7;
            pf0 = fa.v; pf1 = fb.v;
        }

        __builtin_amdgcn_s_setprio(1);
        #pragma unroll
        for (int dt = 0; dt < 4; ++dt) {
            short8_t vf1 = *(const short8_t*)&sVt[buf][16 * dt + l16][quad * 8 + 32];
            oacc[dt] = __builtin_amdgcn_mfma_f32_16x16x32_bf16(pf0, vf0[dt], oacc[dt], 0, 0, 0);
            oacc[dt] = __builtin_amdgcn_mfma_f32_16x16x32_bf16(pf1, vf1, oacc[dt], 0, 0, 0);
        }
        __builtin_amdgcn_s_setprio(0);

        // write next V chunk into the other buffer (K already in flight)
        if (c < ct) {
            union { short8_t v; short4_t h[2]; } u; u.v = vr;
            *(short4_t*)&sVt[buf ^ 1][vdim][P0]     = u.h[0];
            *(short4_t*)&sVt[buf ^ 1][vdim][P0 + 8] = u.h[1];
        }
        __syncthreads();   // drains K DMA (vmcnt) + makes V writes visible
    }

    l_l += __shfl_xor(l_l, 16);
    l_l += __shfl_xor(l_l, 32);

    #pragma unroll
    for (int r = 0; r < 4; ++r) {
        int m = quad * 4 + r;
        float lr = __shfl(l_l, quad * 4 + r);
        float inv = __builtin_amdgcn_rcpf(lr);
        #pragma unroll
        for (int dt = 0; dt < 4; ++dt)
            O[((size_t)b * T_SEQ + tq * 16 + m) * C_DIM + h * HD + 16 * dt + l16] =
                f2bs(oacc[dt][r] * inv);
    }
}

// ---------------------------------------------------------------------------
extern "C" void kernel_launch(void* const* d_in, const int* in_sizes, int n_in,
                              void* d_out, int out_size, void* d_ws, size_t ws_size,
                              hipStream_t stream)
{
    const float* x   = (const float*)d_in[0];
    const float* w_q = (const float*)d_in[1];
    const float* b_q = (const float*)d_in[2];
    const float* w_k = (const float*)d_in[3];
    const float* b_k = (const float*)d_in[4];
    const float* w_v = (const float*)d_in[5];
    const float* b_v = (const float*)d_in[6];
    const float* w_o = (const float*)d_in[7];
    const float* b_o = (const float*)d_in[8];
    float* out = (float*)d_out;

    char* ws = (char*)d_ws;
    short*  Xb   = (short*) (ws);                              // 8 MB
    short*  Ab   = (short*) (ws + ((size_t)8  << 20));         // 8 MB
    short*  QKVb = (short*) (ws + ((size_t)16 << 20));         // 12 MB
    short*  Wqkv = (short*) (ws + ((size_t)28 << 20));         // 3 MB
    short*  Wto  = (short*) (ws + ((size_t)31 << 20));         // 2 MB
    float*  Bqkv = (float*) (ws + ((size_t)33 << 20));         // 6 KB
    float2* Tab  = (float2*)(ws + ((size_t)33 << 20) + 8192);  // 512 KB
    short*  Vt   = (short*) (ws + ((size_t)34 << 20));         // 2 MB

    const int M = MTOK;   // 4096

    prep_kernel<<<6918, 256, 0, stream>>>(
        x, w_q, w_k, w_v, w_o, b_q, b_k, b_v, Xb, Wqkv, Wto, Bqkv, Tab);

    gemm_qkv<<<dim3(QKVW / 128, M / 128), 256, 0, stream>>>(
        Xb, Wqkv, Bqkv, Tab, QKVb, Vt);

    attn_mfma14<<<B_SZ * NKV * 64, 512, 0, stream>>>(QKVb, Vt, Ab);

    gemm_mfma_o<<<dim3(C_DIM / 128, M / 128), 256, 0, stream>>>(
        Ab, Wto, b_o, out, M, C_DIM, C_DIM, 0);
}

// Round 8
// 159.617 us; speedup vs baseline: 1.0810x; 1.0191x over previous
//
#include <hip/hip_runtime.h>
#include <hip/hip_bf16.h>

typedef __hip_bfloat16 bf16;
typedef __attribute__((ext_vector_type(8))) short short8_t;
typedef __attribute__((ext_vector_type(4))) short short4_t;
typedef __attribute__((ext_vector_type(4))) float f32x4;

#define B_SZ   2
#define T_SEQ  2048
#define C_DIM  1024
#define NH     16
#define NKV    4
#define HD     64
#define QKVW   1536          // fused QKV row width (1024 Q | 256 K | 256 V)
#define MTOK   (B_SZ * T_SEQ)

#define LOG2_BASE_OVER_32 0.4152410118609203f
#define Q_SCALE 0.1803368801111204f   // 0.125 * log2(e)

__device__ __forceinline__ short f2bs(float f) {
    unsigned u = __float_as_uint(f);
    u += 0x7FFFu + ((u >> 16) & 1u);
    return (short)(u >> 16);
}
__device__ __forceinline__ short f2bs_trunc(float f) {
    return (short)(__float_as_uint(f) >> 16);
}
__device__ __forceinline__ float bs2f(short s) {
    unsigned u = ((unsigned)(unsigned short)s) << 16;
    return __uint_as_float(u);
}
// lane <-> lane^1 exchange, pure VALU (quad_perm [1,0,3,2])
__device__ __forceinline__ float dpp_xor1(float x) {
    return __int_as_float(
        __builtin_amdgcn_update_dpp(0, __float_as_int(x), 0xB1, 0xF, 0xF, true));
}
// bare v_exp_f32 (2^x)
__device__ __forceinline__ float fast_exp2(float x) {
    float r;
    asm("v_exp_f32 %0, %1" : "=v"(r) : "v"(x));
    return r;
}
// pack hi16(lo), hi16(hi) -> one dword (two bf16, truncating) in 1 v_perm_b32
__device__ __forceinline__ unsigned pack_bf16_trunc(float lo, float hi) {
    return __builtin_amdgcn_perm(__float_as_uint(hi), __float_as_uint(lo),
                                 0x07060302u);
}
// direct HBM -> LDS, 16B per lane. LDS dest = (wave-uniform base) + lane*16.
__device__ __forceinline__ void gload_lds16(const short* g, short* l) {
    __builtin_amdgcn_global_load_lds(
        (const __attribute__((address_space(1))) void*)g,
        (__attribute__((address_space(3))) void*)l, 16, 0, 0);
}

// ---------------------------------------------------------------------------
// Fused prep (unchanged): x->bf16, weight transposes, bias concat, RoPE table
// ---------------------------------------------------------------------------
__device__ __forceinline__ void transpose_tile(
    const float* __restrict__ W, short* __restrict__ Wt,
    int K, int N, int n0, int k0, int tid)
{
    __shared__ float tile[32][33];
    int tx = tid & 31, ty = tid >> 5;
    #pragma unroll
    for (int i = 0; i < 4; ++i)
        tile[ty + 8 * i][tx] = W[(size_t)(k0 + ty + 8 * i) * N + n0 + tx];
    __syncthreads();
    #pragma unroll
    for (int i = 0; i < 4; ++i)
        Wt[(size_t)(n0 + ty + 8 * i) * K + k0 + tx] = f2bs(tile[tx][ty + 8 * i]);
}

__global__ __launch_bounds__(256) void prep_kernel(
    const float* __restrict__ x,
    const float* __restrict__ w_q, const float* __restrict__ w_k,
    const float* __restrict__ w_v, const float* __restrict__ w_o,
    const float* __restrict__ b_q, const float* __restrict__ b_k,
    const float* __restrict__ b_v,
    short* __restrict__ Xb, short* __restrict__ Wqkv, short* __restrict__ Wto,
    float* __restrict__ Bqkv, float2* __restrict__ Tab)
{
    int blk = blockIdx.x, tid = threadIdx.x;
    if (blk < 4096) {
        int i = blk * 1024 + tid * 4;
        float4 v = *(const float4*)(x + i);
        short4_t o;
        o[0] = f2bs(v.x); o[1] = f2bs(v.y); o[2] = f2bs(v.z); o[3] = f2bs(v.w);
        *(short4_t*)(Xb + i) = o;
    } else if (blk < 5120) {
        int l = blk - 4096;
        transpose_tile(w_q, Wqkv, C_DIM, C_DIM, (l & 31) * 32, (l >> 5) * 32, tid);
    } else if (blk < 5376) {
        int l = blk - 5120;
        transpose_tile(w_k, Wqkv + (size_t)1024 * C_DIM, C_DIM, 256,
                       (l & 7) * 32, (l >> 3) * 32, tid);
    } else if (blk < 5632) {
        int l = blk - 5376;
        transpose_tile(w_v, Wqkv + (size_t)1280 * C_DIM, C_DIM, 256,
                       (l & 7) * 32, (l >> 3) * 32, tid);
    } else if (blk < 6656) {
        int l = blk - 5632;
        transpose_tile(w_o, Wto, C_DIM, C_DIM, (l & 31) * 32, (l >> 5) * 32, tid);
    } else if (blk < 6662) {
        int i = (blk - 6656) * 256 + tid;
        float v;
        if (i < 1024)      v = b_q[i];
        else if (i < 1280) v = b_k[i - 1024];
        else               v = b_v[i - 1280];
        Bqkv[i] = v;
    } else {
        int idx = (blk - 6662) * 256 + tid;
        int t = idx >> 5, i = idx & 31;
        float ang = (float)t * exp2f(-(float)i * LOG2_BASE_OVER_32);
        Tab[idx] = make_float2(cosf(ang), sinf(ang));
    }
}

// ---------------------------------------------------------------------------
// 128x128 GEMM K-loop building blocks (unchanged from R6): BK=64,
// global_load_lds staging, XOR-swizzled source + swizzled ds_read, 2-phase
// double-buffer with counted vmcnt(8).
// ---------------------------------------------------------------------------
#define GEMM_STAGE(dstA, dstB, Aptr, Bptr, k0)                                  \
    {                                                                           \
        _Pragma("unroll")                                                       \
        for (int it = 0; it < 4; ++it) {                                        \
            int i = (w * 4 + it) * 64 + lane;                                   \
            int row = i >> 3, p = i & 7;                                        \
            int gc = (k0) + ((p ^ (row & 7)) << 3);                             \
            gload_lds16((Aptr) + (size_t)(m0 + row) * K + gc,                   \
                        (dstA) + (w * 4 + it) * 512);                           \
        }                                                                       \
        _Pragma("unroll")                                                       \
        for (int it = 0; it < 4; ++it) {                                        \
            int i = (w * 4 + it) * 64 + lane;                                   \
            int row = i >> 3, p = i & 7;                                        \
            int gc = (k0) + ((p ^ (row & 7)) << 3);                             \
            gload_lds16((Bptr) + (size_t)(n0 + row) * K + gc,                   \
                        (dstB) + (w * 4 + it) * 512);                           \
        }                                                                       \
    }

#define GEMM_COMPUTE(srcA, srcB)                                                \
    {                                                                           \
        _Pragma("unroll")                                                       \
        for (int ks = 0; ks < 2; ++ks) {                                        \
            short8_t af[4], bf[4];                                              \
            _Pragma("unroll")                                                   \
            for (int mt = 0; mt < 4; ++mt) {                                    \
                int r = wm * 64 + mt * 16 + l16;                                \
                int g = ks * 4 + quad;                                          \
                af[mt] = *(const short8_t*)&(srcA)[r * 64 + ((g ^ (r & 7)) << 3)]; \
            }                                                                   \
            _Pragma("unroll")                                                   \
            for (int nt = 0; nt < 4; ++nt) {                                    \
                int r = wn * 64 + nt * 16 + l16;                                \
                int g = ks * 4 + quad;                                          \
                bf[nt] = *(const short8_t*)&(srcB)[r * 64 + ((g ^ (r & 7)) << 3)]; \
            }                                                                   \
            _Pragma("unroll")                                                   \
            for (int mt = 0; mt < 4; ++mt)                                      \
                _Pragma("unroll")                                               \
                for (int nt = 0; nt < 4; ++nt)                                  \
                    acc[mt][nt] = __builtin_amdgcn_mfma_f32_16x16x32_bf16(      \
                        af[mt], bf[nt], acc[mt][nt], 0, 0, 0);                  \
        }                                                                       \
    }

#define GEMM_KLOOP(Aptr, Bptr)                                                  \
    GEMM_STAGE(sA(0), sB(0), Aptr, Bptr, 0);                                    \
    for (int t = 0; t < NT; ++t) {                                              \
        int cur = t & 1;                                                        \
        if (t + 1 < NT) {                                                       \
            GEMM_STAGE(sA(cur ^ 1), sB(cur ^ 1), Aptr, Bptr, (t + 1) * 64);     \
            asm volatile("s_waitcnt vmcnt(8)" ::: "memory");                    \
        } else {                                                                \
            asm volatile("s_waitcnt vmcnt(0)" ::: "memory");                    \
        }                                                                       \
        __builtin_amdgcn_s_barrier();                                           \
        __builtin_amdgcn_sched_barrier(0);                                      \
        GEMM_COMPUTE(sA(cur), sB(cur));                                         \
        __builtin_amdgcn_sched_barrier(0);                                      \
        __builtin_amdgcn_s_barrier();                                           \
    }

// ---------------------------------------------------------------------------
// QKV GEMM (unchanged from R6): 128x128 tile, counted-vmcnt 2-phase.
// ---------------------------------------------------------------------------
__global__ __launch_bounds__(256) void gemm_qkv(
    const short* __restrict__ A, const short* __restrict__ Bt,
    const float* __restrict__ bias, const float2* __restrict__ Tab,
    short* __restrict__ QKVb, short* __restrict__ Vt)
{
    __shared__ __align__(16) short smem[32768];     // 64 KB: 2 x (A 8K | B 8K)
    #define sA(b) (smem + (b) * 16384)
    #define sB(b) (smem + (b) * 16384 + 8192)

    const int K = C_DIM, NT = C_DIM / 64;
    int m0 = blockIdx.y * 128;
    int n0 = blockIdx.x * 128;
    int tid  = threadIdx.x;
    int w    = tid >> 6, lane = tid & 63;
    int quad = lane >> 4, l16 = lane & 15;
    int wm = w & 1, wn = w >> 1;

    f32x4 acc[4][4] = {};

    GEMM_KLOOP(A, Bt);

    if (n0 < 1280) {
        // Q or K: bias + RoPE (+ Q_SCALE for Q)
        float scale = (n0 < 1024) ? Q_SCALE : 1.0f;
        float sgn   = (l16 & 1) ? 1.0f : -1.0f;
        #pragma unroll
        for (int nt = 0; nt < 4; ++nt) {
            int col = n0 + wn * 64 + nt * 16 + l16;
            int ip  = (col & 63) >> 1;
            float bv = bias[col];
            #pragma unroll
            for (int mt = 0; mt < 4; ++mt) {
                #pragma unroll
                for (int r = 0; r < 4; ++r) {
                    int row = m0 + wm * 64 + mt * 16 + quad * 4 + r;
                    float v = acc[mt][nt][r] + bv;
                    float po = dpp_xor1(v);
                    float2 cs = Tab[(row & (T_SEQ - 1)) * 32 + ip];
                    float res = (v * cs.x + sgn * po * cs.y) * scale;
                    QKVb[(size_t)row * QKVW + col] = f2bs(res);
                }
            }
        }
    } else {
        // V: bias + transpose -> Vt[d][token], two 64-dim passes through LDS
        short (*sT)[136] = (short(*)[136])smem;    // 64 x 136 shorts
        #pragma unroll
        for (int h2 = 0; h2 < 2; ++h2) {
            if (wn == h2) {
                #pragma unroll
                for (int nt = 0; nt < 4; ++nt) {
                    int col_l = nt * 16 + l16;             // 0..63
                    float bv = bias[n0 + h2 * 64 + col_l];
                    #pragma unroll
                    for (int mt = 0; mt < 4; ++mt)
                        #pragma unroll
                        for (int r = 0; r < 4; ++r)
                            sT[col_l][wm * 64 + mt * 16 + quad * 4 + r] =
                                f2bs(acc[mt][nt][r] + bv);
                }
            }
            __syncthreads();
            int d0 = n0 - 1280 + h2 * 64;
            #pragma unroll
            for (int it = 0; it < 4; ++it) {
                int slot = tid + 256 * it;                 // 64 dims x 16 segs
                int dl = slot >> 4, seg = (slot & 15) * 8;
                *(short8_t*)(Vt + (size_t)(d0 + dl) * MTOK + m0 + seg) =
                    *(const short8_t*)&sT[dl][seg];
            }
            __syncthreads();
        }
    }
    #undef sA
    #undef sB
}

// ---------------------------------------------------------------------------
// O-projection GEMM (unchanged from R6): 128x128 tile, counted-vmcnt 2-phase
// ---------------------------------------------------------------------------
__global__ __launch_bounds__(256) void gemm_mfma_o(
    const short* __restrict__ A, const short* __restrict__ Bt,
    const float* __restrict__ bias, float* __restrict__ C,
    int M, int N, int K_, int unused)
{
    __shared__ __align__(16) short smem[32768];
    #define sA(b) (smem + (b) * 16384)
    #define sB(b) (smem + (b) * 16384 + 8192)

    const int K = C_DIM, NT = C_DIM / 64;
    int m0 = blockIdx.y * 128;
    int n0 = blockIdx.x * 128;
    int tid  = threadIdx.x;
    int w    = tid >> 6, lane = tid & 63;
    int quad = lane >> 4, l16 = lane & 15;
    int wm = w & 1, wn = w >> 1;

    f32x4 acc[4][4] = {};

    GEMM_KLOOP(A, Bt);

    #pragma unroll
    for (int mt = 0; mt < 4; ++mt) {
        #pragma unroll
        for (int nt = 0; nt < 4; ++nt) {
            int col = n0 + wn * 64 + nt * 16 + l16;
            float bv = bias[col];
            #pragma unroll
            for (int r = 0; r < 4; ++r) {
                int row = m0 + wm * 64 + mt * 16 + quad * 4 + r;
                C[(size_t)row * N + col] = acc[mt][nt][r] + bv;
            }
        }
    }
    #undef sA
    #undef sB
}

// ---------------------------------------------------------------------------
// MFMA flash attention v15 = v14 (8-wave paired blocks, K-DMA staging) +
// CROSS-CHUNK SOFTWARE PIPELINE. The loop is shifted so QK^T(c+1) (MFMA)
// and softmax(c) (VALU) sit adjacent between the same barrier pair — the
// scheduler interleaves the two independent streams, filling the >50% idle
// issue slots R7 exposed. Region R_c (between barriers B_c, B_{c+1}):
//   QK(c+1) reads sK[(c+1)&1]  |  DMA K(c+2) writes sK[c&1]      (disjoint)
//   PV(c)   reads sVt[c&1]     |  V(c+1) write  sVt[(c+1)&1]     (disjoint)
// __syncthreads at B_{c+1} drains the K DMA and publishes V(c+1).
// Extra state: second sacc set (+16 VGPR).
// ---------------------------------------------------------------------------
__global__ __launch_bounds__(512) void attn_mfma15(
    const short* __restrict__ QKV, const short* __restrict__ Vt,
    short* __restrict__ O)
{
    __shared__ __align__(16) short sK [2][64][64];   // swizzled granules, no pad
    __shared__ __align__(16) short sVt[2][64][72];   // padded, perm'd tokens

    const int tid  = threadIdx.x;          // 0..511
    const int w    = tid >> 6;             // 0..7
    const int lane = tid & 63;
    const int quad = lane >> 4;
    const int l16  = lane & 15;

    int blk = blockIdx.x;
    int grp = blk & 7;                     // (b,kvh)
    int pr  = 63 - (blk >> 3);             // pair index, long pairs first
    int kvh = grp & 3;
    int b   = grp >> 2;
    int h   = kvh * 4 + (w & 3);
    int tq  = pr * 2 + (w >> 2);           // waves 0-3: tile A, 4-7: tile B
    int ct  = pr >> 1;                     // == tq>>2 for both tiles
    int tg  = tq * 16 + l16;

    // Q frags (already roped + scaled)
    const short* qptr = QKV + ((size_t)(b * T_SEQ) + tq * 16 + l16) * QKVW + h * HD;
    short8_t qf0 = *(const short8_t*)(qptr + quad * 8);
    short8_t qf1 = *(const short8_t*)(qptr + quad * 8 + 32);

    const short* kbase  = QKV + (size_t)b * T_SEQ * QKVW + 1024 + kvh * HD;
    const short* vtbase = Vt + (size_t)(kvh * HD) * MTOK + b * T_SEQ;

    float m_l = -INFINITY, l_l = 0.f;      // quad-partial row sum
    f32x4 oacc[4];
    #pragma unroll
    for (int dt = 0; dt < 4; ++dt) oacc[dt] = (f32x4){0.f, 0.f, 0.f, 0.f};

    // K DMA staging indices (512 threads cover the 64x64 tile, 16B each)
    const int kr_  = tid >> 3;              // row 0..63
    const int kg   = tid & 7;               // dest granule
    const int ksrc = (kg ^ (kr_ & 7)) << 3; // pre-swizzled source col

    // V reg staging indices (512 threads cover the 64x64 tile)
    const int vdim = tid >> 3;              // 0..63
    const int s8   = tid & 7;
    const int vseg = s8 * 8;
    const int P0   = ((s8 & 4) << 3) | ((s8 & 1) << 4) | ((s8 & 2) << 1);

    // swizzled K read granule (row&7 == l16&7 since rows are l16+16kt)
    const int c0g = quad ^ (l16 & 7);

    // ---- prologue: K(0),V(0) staged; K(1) in flight; V(1) in vr; S(0) ----
    gload_lds16(kbase + (size_t)kr_ * QKVW + ksrc, (short*)sK[0] + (w << 9));
    {
        short8_t v0 = *(const short8_t*)(vtbase + (size_t)vdim * MTOK + vseg);
        union { short8_t v; short4_t h[2]; } u; u.v = v0;
        *(short4_t*)&sVt[0][vdim][P0]     = u.h[0];
        *(short4_t*)&sVt[0][vdim][P0 + 8] = u.h[1];
    }
    short8_t vr;
    if (ct > 0) {
        gload_lds16(kbase + (size_t)(64 + kr_) * QKVW + ksrc,
                    (short*)sK[1] + (w << 9));
        vr = *(const short8_t*)(vtbase + (size_t)vdim * MTOK + 64 + vseg);
    }
    __syncthreads();                        // K(0),V(0) visible; K(1) in flight

    f32x4 sacc[4], sacc_n[4];
    #pragma unroll
    for (int kt = 0; kt < 4; ++kt) {
        f32x4 z = {0.f, 0.f, 0.f, 0.f};
        const short* krow = &sK[0][l16 + 16 * kt][0];
        short8_t kf0 = *(const short8_t*)(krow + (c0g << 3));
        short8_t kf1 = *(const short8_t*)(krow + ((c0g ^ 4) << 3));
        z = __builtin_amdgcn_mfma_f32_16x16x32_bf16(kf0, qf0, z, 0, 0, 0);
        z = __builtin_amdgcn_mfma_f32_16x16x32_bf16(kf1, qf1, z, 0, 0, 0);
        sacc[kt] = z;
    }

    for (int c = 0; c <= ct; ++c) {
        const int buf = c & 1;
        __syncthreads();                    // B_c: K(c+1) drained, V(c) (and
                                            // V(c+1)-writes of R_{c-1}) visible

        __builtin_amdgcn_s_setprio(1);
        // QK(c+1): independent MFMA stream — interleaves with softmax(c) below
        if (c < ct) {
            #pragma unroll
            for (int kt = 0; kt < 4; ++kt) {
                f32x4 z = {0.f, 0.f, 0.f, 0.f};
                const short* krow = &sK[buf ^ 1][l16 + 16 * kt][0];
                short8_t kf0 = *(const short8_t*)(krow + (c0g << 3));
                short8_t kf1 = *(const short8_t*)(krow + ((c0g ^ 4) << 3));
                z = __builtin_amdgcn_mfma_f32_16x16x32_bf16(kf0, qf0, z, 0, 0, 0);
                z = __builtin_amdgcn_mfma_f32_16x16x32_bf16(kf1, qf1, z, 0, 0, 0);
                sacc_n[kt] = z;
            }
            if (c + 2 <= ct) {
                int jn = (c + 2) * 64;
                gload_lds16(kbase + (size_t)(jn + kr_) * QKVW + ksrc,
                            (short*)sK[buf] + (w << 9));
            }
        }

        // mask the CURRENT chunk's scores on the causal diagonal
        if (c == ct) {
            int j0 = c * 64;
            #pragma unroll
            for (int kt = 0; kt < 4; ++kt)
                #pragma unroll
                for (int r = 0; r < 4; ++r)
                    if (j0 + 16 * kt + quad * 4 + r > tg) sacc[kt][r] = -INFINITY;
        }

        // ---- softmax(c) on sacc (VALU; overlaps QK(c+1) MFMAs) ----
        float v0 = fmaxf(fmaxf(sacc[0][0], sacc[0][1]), fmaxf(sacc[0][2], sacc[0][3]));
        float v1 = fmaxf(fmaxf(sacc[1][0], sacc[1][1]), fmaxf(sacc[1][2], sacc[1][3]));
        float v2 = fmaxf(fmaxf(sacc[2][0], sacc[2][1]), fmaxf(sacc[2][2], sacc[2][3]));
        float v3 = fmaxf(fmaxf(sacc[3][0], sacc[3][1]), fmaxf(sacc[3][2], sacc[3][3]));
        float vloc = fmaxf(fmaxf(v0, v1), fmaxf(v2, v3));

        if (!__all(vloc <= m_l + 8.0f)) {
            float vmax = fmaxf(vloc, __shfl_xor(vloc, 16));
            vmax = fmaxf(vmax, __shfl_xor(vmax, 32));
            float mnew = fmaxf(m_l, vmax);
            float al = fast_exp2(m_l - mnew);
            m_l = mnew;
            l_l *= al;
            #pragma unroll
            for (int r = 0; r < 4; ++r) {
                float alr = __shfl(al, quad * 4 + r);
                #pragma unroll
                for (int dt = 0; dt < 4; ++dt) oacc[dt][r] *= alr;
            }
        }

        float psum = 0.f;
        unsigned pk0, pk1, pk2, pk3, pk4, pk5, pk6, pk7;
        {
            float p0 = fast_exp2(sacc[0][0] - m_l), p1 = fast_exp2(sacc[0][1] - m_l);
            float p2 = fast_exp2(sacc[0][2] - m_l), p3 = fast_exp2(sacc[0][3] - m_l);
            psum += (p0 + p1) + (p2 + p3);
            pk0 = pack_bf16_trunc(p0, p1); pk1 = pack_bf16_trunc(p2, p3);
        }
        {
            float p0 = fast_exp2(sacc[1][0] - m_l), p1 = fast_exp2(sacc[1][1] - m_l);
            float p2 = fast_exp2(sacc[1][2] - m_l), p3 = fast_exp2(sacc[1][3] - m_l);
            psum += (p0 + p1) + (p2 + p3);
            pk2 = pack_bf16_trunc(p0, p1); pk3 = pack_bf16_trunc(p2, p3);
        }
        {
            float p0 = fast_exp2(sacc[2][0] - m_l), p1 = fast_exp2(sacc[2][1] - m_l);
            float p2 = fast_exp2(sacc[2][2] - m_l), p3 = fast_exp2(sacc[2][3] - m_l);
            psum += (p0 + p1) + (p2 + p3);
            pk4 = pack_bf16_trunc(p0, p1); pk5 = pack_bf16_trunc(p2, p3);
        }
        {
            float p0 = fast_exp2(sacc[3][0] - m_l), p1 = fast_exp2(sacc[3][1] - m_l);
            float p2 = fast_exp2(sacc[3][2] - m_l), p3 = fast_exp2(sacc[3][3] - m_l);
            psum += (p0 + p1) + (p2 + p3);
            pk6 = pack_bf16_trunc(p0, p1); pk7 = pack_bf16_trunc(p2, p3);
        }
        l_l += psum;

        short8_t pf0, pf1;
        {
            union { unsigned u[4]; short8_t v; } fa, fb;
            fa.u[0] = pk0; fa.u[1] = pk1; fa.u[2] = pk2; fa.u[3] = pk3;
            fb.u[0] = pk4; fb.u[1] = pk5; fb.u[2] = pk6; fb.u[3] = pk7;
            pf0 = fa.v; pf1 = fb.v;
        }

        // V(c+1) write + V(c+2) load issue (hidden under PV)
        if (c < ct) {
            union { short8_t v; short4_t hh[2]; } u; u.v = vr;
            *(short4_t*)&sVt[buf ^ 1][vdim][P0]     = u.hh[0];
            *(short4_t*)&sVt[buf ^ 1][vdim][P0 + 8] = u.hh[1];
            if (c + 2 <= ct)
                vr = *(const short8_t*)(vtbase + (size_t)vdim * MTOK
                                        + (c + 2) * 64 + vseg);
        }

        // ---- PV(c) ----
        #pragma unroll
        for (int dt = 0; dt < 4; ++dt) {
            short8_t vf0 = *(const short8_t*)&sVt[buf][16 * dt + l16][quad * 8];
            short8_t vf1 = *(const short8_t*)&sVt[buf][16 * dt + l16][quad * 8 + 32];
            oacc[dt] = __builtin_amdgcn_mfma_f32_16x16x32_bf16(pf0, vf0, oacc[dt], 0, 0, 0);
            oacc[dt] = __builtin_amdgcn_mfma_f32_16x16x32_bf16(pf1, vf1, oacc[dt], 0, 0, 0);
        }
        __builtin_amdgcn_s_setprio(0);

        // rotate S-tiles
        #pragma unroll
        for (int kt = 0; kt < 4; ++kt) sacc[kt] = sacc_n[kt];
    }

    l_l += __shfl_xor(l_l, 16);
    l_l += __shfl_xor(l_l, 32);

    #pragma unroll
    for (int r = 0; r < 4; ++r) {
        int m = quad * 4 + r;
        float lr = __shfl(l_l, quad * 4 + r);
        float inv = __builtin_amdgcn_rcpf(lr);
        #pragma unroll
        for (int dt = 0; dt < 4; ++dt)
            O[((size_t)b * T_SEQ + tq * 16 + m) * C_DIM + h * HD + 16 * dt + l16] =
                f2bs(oacc[dt][r] * inv);
    }
}

// ---------------------------------------------------------------------------
extern "C" void kernel_launch(void* const* d_in, const int* in_sizes, int n_in,
                              void* d_out, int out_size, void* d_ws, size_t ws_size,
                              hipStream_t stream)
{
    const float* x   = (const float*)d_in[0];
    const float* w_q = (const float*)d_in[1];
    const float* b_q = (const float*)d_in[2];
    const float* w_k = (const float*)d_in[3];
    const float* b_k = (const float*)d_in[4];
    const float* w_v = (const float*)d_in[5];
    const float* b_v = (const float*)d_in[6];
    const float* w_o = (const float*)d_in[7];
    const float* b_o = (const float*)d_in[8];
    float* out = (float*)d_out;

    char* ws = (char*)d_ws;
    short*  Xb   = (short*) (ws);                              // 8 MB
    short*  Ab   = (short*) (ws + ((size_t)8  << 20));         // 8 MB
    short*  QKVb = (short*) (ws + ((size_t)16 << 20));         // 12 MB
    short*  Wqkv = (short*) (ws + ((size_t)28 << 20));         // 3 MB
    short*  Wto  = (short*) (ws + ((size_t)31 << 20));         // 2 MB
    float*  Bqkv = (float*) (ws + ((size_t)33 << 20));         // 6 KB
    float2* Tab  = (float2*)(ws + ((size_t)33 << 20) + 8192);  // 512 KB
    short*  Vt   = (short*) (ws + ((size_t)34 << 20));         // 2 MB

    const int M = MTOK;   // 4096

    prep_kernel<<<6918, 256, 0, stream>>>(
        x, w_q, w_k, w_v, w_o, b_q, b_k, b_v, Xb, Wqkv, Wto, Bqkv, Tab);

    gemm_qkv<<<dim3(QKVW / 128, M / 128), 256, 0, stream>>>(
        Xb, Wqkv, Bqkv, Tab, QKVb, Vt);

    attn_mfma15<<<B_SZ * NKV * 64, 512, 0, stream>>>(QKVb, Vt, Ab);

    gemm_mfma_o<<<dim3(C_DIM / 128, M / 128), 256, 0, stream>>>(
        Ab, Wto, b_o, out, M, C_DIM, C_DIM, 0);
}